// Round 3
// baseline (3760.787 us; speedup 1.0000x reference)
//
#include <hip/hip_runtime.h>
#include <hip/hip_bf16.h>

#define D_    768
#define P_    1536
#define HID_  768
#define NH_   8
#define DH_   96
#define S_    2048

typedef __hip_bfloat16 bf16_t;
typedef __attribute__((ext_vector_type(8))) short s16x8;
typedef __attribute__((ext_vector_type(8))) unsigned short u16x8;
typedef __attribute__((ext_vector_type(4))) float f32x4;

__device__ __forceinline__ unsigned short f2b(float f) {
    bf16_t h = __float2bfloat16(f);
    unsigned short u; __builtin_memcpy(&u, &h, 2); return u;
}

// async global->LDS, 16B per lane (LDS dest = wave-uniform base + lane*16, linear layout)
__device__ __forceinline__ void gload16(const void* g, const void* l) {
    __builtin_amdgcn_global_load_lds(
        (const __attribute__((address_space(1))) unsigned int*)(unsigned long long)(g),
        (__attribute__((address_space(3))) unsigned int*)(unsigned int)(unsigned long long)(l),
        16, 0, 0);
}

// ---------------- fp32 -> bf16 (single) ----------------
__global__ void cvt_kernel(const float* __restrict__ src, bf16_t* __restrict__ dst, int n) {
    int i = blockIdx.x * blockDim.x + threadIdx.x;
    int stride = gridDim.x * blockDim.x;
    for (; i < n; i += stride) dst[i] = __float2bfloat16(src[i]);
}

// ---------------- fp32 -> bf16 hi/lo split ----------------
__global__ void cvt2_kernel(const float* __restrict__ src, bf16_t* __restrict__ hi,
                            bf16_t* __restrict__ lo, int n) {
    int i = blockIdx.x * blockDim.x + threadIdx.x;
    int stride = gridDim.x * blockDim.x;
    for (; i < n; i += stride) {
        float x = src[i];
        bf16_t h = __float2bfloat16(x);
        hi[i] = h;
        lo[i] = __float2bfloat16(x - __bfloat162float(h));
    }
}

// ---------------- LayerNorm(x) -> bf16 hi/lo pair rows [hi 768 | lo 768] ----------------
__global__ __launch_bounds__(256) void ln_x_kernel(const float* __restrict__ x,
                                                   const float* __restrict__ w,
                                                   const float* __restrict__ b,
                                                   bf16_t* __restrict__ xn) {
    const int t = blockIdx.x, tid = threadIdx.x;
    const size_t rb = (size_t)t * D_;
    float v0 = x[rb + tid], v1 = x[rb + tid + 256], v2 = x[rb + tid + 512];
    float sm = v0 + v1 + v2;
    float sq = v0 * v0 + v1 * v1 + v2 * v2;
#pragma unroll
    for (int off = 32; off > 0; off >>= 1) { sm += __shfl_xor(sm, off); sq += __shfl_xor(sq, off); }
    __shared__ float ws4[8];
    const int wid = tid >> 6, lane = tid & 63;
    if (lane == 0) { ws4[wid] = sm; ws4[4 + wid] = sq; }
    __syncthreads();
    sm = ws4[0] + ws4[1] + ws4[2] + ws4[3];
    sq = ws4[4] + ws4[5] + ws4[6] + ws4[7];
    const float mu = sm * (1.f / D_);
    const float rs = rsqrtf(sq * (1.f / D_) - mu * mu + 1e-6f);
    bf16_t* row = xn + (size_t)t * 1536;
#pragma unroll
    for (int k2 = 0; k2 < 3; ++k2) {
        const int c = tid + k2 * 256;
        const float v = (k2 == 0 ? v0 : k2 == 1 ? v1 : v2);
        const float y = (v - mu) * rs * w[c] + b[c];
        bf16_t h = __float2bfloat16(y);
        row[c] = h;
        row[768 + c] = __float2bfloat16(y - __bfloat162float(h));
    }
}

// ---------------- conv(K=4)+SiLU from fp32 xl; writes compact xc-hi plane; fp32 gates fused ----------------
__global__ __launch_bounds__(192) void conv_gate_kernel(const float* __restrict__ xl,
                                                        const float* __restrict__ cw,
                                                        const float* __restrict__ fw,
                                                        const float* __restrict__ fb,
                                                        bf16_t* __restrict__ xch,
                                                        float* __restrict__ gates) {
    const int t = blockIdx.x, c = threadIdx.x;   // c: 8-float chunk, 192*8 = 1536
    const float* row = xl + (size_t)t * P_;
    const float4* r4 = (const float4*)row;
    float4 a = r4[2 * c], b4 = r4[2 * c + 1];
    float pm3 = 0.f, pm2 = 0.f, pm1 = 0.f;
    if (c > 0) { pm3 = row[c * 8 - 3]; pm2 = row[c * 8 - 2]; pm1 = row[c * 8 - 1]; }
    const float w0 = cw[0], w1 = cw[1], w2 = cw[2], w3 = cw[3];
    float xv[11] = {pm3, pm2, pm1, a.x, a.y, a.z, a.w, b4.x, b4.y, b4.z, b4.w};
    float xc[8];
    u16x8 h8;
#pragma unroll
    for (int j = 0; j < 8; ++j) {
        float s = w0 * xv[j] + w1 * xv[j + 1] + w2 * xv[j + 2] + w3 * xv[j + 3];
        s = s * (1.f / (1.f + __expf(-s)));   // SiLU
        xc[j] = s;
        h8[j] = f2b(s);
    }
    *(u16x8*)(xch + (size_t)t * P_ + c * 8) = h8;

    // fused exact-fp32 gate dots: z_j = sum_p xc_p * fw[j*1536+p], j = 0..15
    float pj[16];
#pragma unroll
    for (int j = 0; j < 16; ++j) {
        const float* wr = fw + (size_t)j * P_ + c * 8;
        float p = 0.f;
#pragma unroll
        for (int u = 0; u < 8; ++u) p += xc[u] * wr[u];
        pj[j] = p;
    }
#pragma unroll
    for (int j = 0; j < 16; ++j)
#pragma unroll
        for (int off = 32; off > 0; off >>= 1) pj[j] += __shfl_xor(pj[j], off);
    __shared__ float red[3][16];
    const int wv = c >> 6, ln = c & 63;
    if (ln == 0) {
#pragma unroll
        for (int j = 0; j < 16; ++j) red[wv][j] = pj[j];
    }
    __syncthreads();
    if (c < 16) {
        const float z = red[0][c] + red[1][c] + red[2][c] + fb[c];
        gates[(size_t)t * 16 + c] = 15.f * tanhf(z * (1.f / 15.f));
    }
}

// ---------------- 128x128 bf16 MFMA GEMM, C = A[M,K] * W[N,K]^T, multi-pass split ----------------
// pass 0: Ah*Wh; pass 1: Ah*Wl; pass 2: (A+aloff)*Wh.
// MODE 0: bf16 out0[grow*ldout+gcol]
// MODE 1: fp32 outf[grow*ldout+gcol]
// MODE 2: qkvo epilogue (+bias): seg0 sigmoid->o, seg1 q, seg2 k/sqrt(96), seg3 v (all bf16)
// MODE 3: fp32 outf = acc + resid
template <int NPASS, int MODE>
__global__ __launch_bounds__(256) void gemm_k(
    const char* __restrict__ Ab, int astride, int aloff,
    const bf16_t* __restrict__ Wh, const bf16_t* __restrict__ Wl, int K,
    bf16_t* __restrict__ out0, float* __restrict__ outf, int ldout,
    bf16_t* __restrict__ oq, bf16_t* __restrict__ ok, bf16_t* __restrict__ ov,
    const float* __restrict__ bias, const float* __restrict__ resid) {
    __shared__ bf16_t smA[128 * 64];
    __shared__ bf16_t smB[128 * 64];
    const int tid = threadIdx.x;
    const int mt = blockIdx.y, nt = blockIdx.x;
    const int wid = tid >> 6, lane = tid & 63;
    const int wm = wid >> 1, wn = wid & 1;
    const int l15 = lane & 15, l4 = lane >> 4;

    f32x4 acc[4][4];
#pragma unroll
    for (int i = 0; i < 4; ++i)
#pragma unroll
        for (int j = 0; j < 4; ++j) acc[i][j] = f32x4{0.f, 0.f, 0.f, 0.f};

    const int trow = tid >> 3;   // 0..31
    const int tcc = tid & 7;
    const int KT = K >> 6;

    for (int pass = 0; pass < NPASS; ++pass) {
        const char* ap = Ab + (pass == 2 ? aloff : 0);
        const bf16_t* wp = (pass == 1) ? Wl : Wh;
        for (int kt = 0; kt < KT; ++kt) {
            const int k0 = kt << 6;
            __syncthreads();
#pragma unroll
            for (int rr = 0; rr < 4; ++rr) {
                const int row = rr * 32 + trow;
                const int loff = (rr * 256 + tid) * 16;
                gload16(ap + (size_t)(mt * 128 + row) * astride + (size_t)(k0 + tcc * 8) * 2,
                        (const char*)smA + loff);
                gload16((const char*)wp + ((size_t)(nt * 128 + row) * K + k0 + tcc * 8) * 2,
                        (const char*)smB + loff);
            }
            __syncthreads();
#pragma unroll
            for (int kk = 0; kk < 2; ++kk) {
                s16x8 af[4], bfr[4];
#pragma unroll
                for (int i = 0; i < 4; ++i) {
                    const int ar = wm * 64 + i * 16 + l15;
                    af[i] = *(const s16x8*)((const char*)smA + ar * 128 + kk * 64 + l4 * 16);
                    const int br = wn * 64 + i * 16 + l15;
                    bfr[i] = *(const s16x8*)((const char*)smB + br * 128 + kk * 64 + l4 * 16);
                }
#pragma unroll
                for (int i = 0; i < 4; ++i)
#pragma unroll
                    for (int j = 0; j < 4; ++j)
                        acc[i][j] = __builtin_amdgcn_mfma_f32_16x16x32_bf16(af[i], bfr[j], acc[i][j], 0, 0, 0);
            }
        }
    }

    const int grow0 = mt * 128 + wm * 64;
    const int gcol0 = nt * 128 + wn * 64;
#pragma unroll
    for (int i = 0; i < 4; ++i) {
#pragma unroll
        for (int j = 0; j < 4; ++j) {
            const int gcol = gcol0 + j * 16 + l15;
#pragma unroll
            for (int r = 0; r < 4; ++r) {
                const int grow = grow0 + i * 16 + l4 * 4 + r;
                float v = acc[i][j][r];
                if constexpr (MODE == 0) {
                    out0[(size_t)grow * ldout + gcol] = __float2bfloat16(v);
                } else if constexpr (MODE == 1) {
                    outf[(size_t)grow * ldout + gcol] = v;
                } else if constexpr (MODE == 2) {
                    v += bias[gcol];
                    const int seg = gcol / 768;          // uniform per block (768 % 128 == 0)
                    const int col = gcol - seg * 768;
                    const size_t oo = (size_t)grow * 768 + col;
                    if (seg == 0)      out0[oo] = __float2bfloat16(1.f / (1.f + __expf(-v)));
                    else if (seg == 1) oq[oo] = __float2bfloat16(v);
                    else if (seg == 2) ok[oo] = __float2bfloat16(v * 0.10206207261596577f); // 1/sqrt(96)
                    else               ov[oo] = __float2bfloat16(v);
                } else {
                    const size_t oo = (size_t)grow * ldout + gcol;
                    outf[oo] = v + resid[oo];
                }
            }
        }
    }
}

// ---------------- sequential mLSTM recurrence, one block per (b,h) ----------------
__global__ __launch_bounds__(384) void recur_kernel(
    const float* __restrict__ gates,
    const bf16_t* __restrict__ qb, const bf16_t* __restrict__ kb,
    const bf16_t* __restrict__ vb, const bf16_t* __restrict__ ob,
    float* __restrict__ hb) {
    const int bh = blockIdx.x;
    const int b = bh >> 3, hd = bh & 7;
    const int tid = threadIdx.x;
    const int s = tid / 96;
    const int d = tid - s * 96;
    const int e0 = s * 24;

    __shared__ float2 kq[96];
    __shared__ float pnum[384];
    __shared__ float red[2];

    float C[24];
#pragma unroll
    for (int j = 0; j < 24; ++j) C[j] = 0.f;
    float n_d = 1.0f;
    float m_run = 0.f;

    const size_t tokbase = (size_t)b * S_;
    const size_t vecbase = tokbase * HID_ + hd * DH_ + d;

    float cq = 0.f, ck = 0.f, cv, co = 0.f, ci, cf;
    {
        cv = __bfloat162float(vb[vecbase]);
        if (s == 0) {
            cq = __bfloat162float(qb[vecbase]);
            ck = __bfloat162float(kb[vecbase]);
            co = __bfloat162float(ob[vecbase]);
        }
        const float* g = gates + tokbase * 16;
        ci = g[hd]; cf = g[8 + hd];
    }

    for (int t = 0; t < S_; ++t) {
        float nq = 0.f, nk = 0.f, nv = 0.f, no = 0.f, ni = 0.f, nf = 0.f;
        if (t + 1 < S_) {
            const size_t idx = vecbase + (size_t)(t + 1) * HID_;
            nv = __bfloat162float(vb[idx]);
            if (s == 0) {
                nq = __bfloat162float(qb[idx]);
                nk = __bfloat162float(kb[idx]);
                no = __bfloat162float(ob[idx]);
            }
            const float* g = gates + (tokbase + t + 1) * 16;
            ni = g[hd]; nf = g[8 + hd];
        }
        if (s == 0) kq[d] = make_float2(ck, cq);
        __syncthreads();

        const float m_new = fmaxf(cf + m_run, ci);
        const float ig = __expf(ci - m_new);
        const float fg = __expf(cf - m_new + m_run);
        m_run = m_new;
        const float a = ig * cv;

        float pn = 0.f;
#pragma unroll
        for (int j = 0; j < 24; ++j) {
            const float2 t2 = kq[e0 + j];
            C[j] = fg * C[j] + a * t2.x;
            pn += C[j] * t2.y;
        }
        pnum[tid] = pn;

        float dp = 0.f;
        if (s == 0) {
            n_d = fg * n_d + ig * ck;
            dp = n_d * cq;
        }
#pragma unroll
        for (int off = 32; off > 0; off >>= 1) dp += __shfl_xor(dp, off);
        if (tid == 0)  red[0] = dp;
        if (tid == 64) red[1] = dp;
        __syncthreads();

        if (s == 0) {
            const float num = pnum[d] + pnum[96 + d] + pnum[192 + d] + pnum[288 + d];
            float den = fmaxf(red[0] + red[1], 1.0f);
            hb[vecbase + (size_t)t * HID_] = co * num / den;
        }
        cq = nq; ck = nk; cv = nv; co = no; ci = ni; cf = nf;
    }
}

// ---------------- (LN(h)+skip)*silu(r) -> pre hi/lo pair rows ----------------
__global__ __launch_bounds__(256) void epi1_kernel(const float* __restrict__ h,
                                                   const bf16_t* __restrict__ xskip,
                                                   const bf16_t* __restrict__ r,
                                                   const float* __restrict__ hw,
                                                   const float* __restrict__ hbi,
                                                   bf16_t* __restrict__ pre) {
    const int t = blockIdx.x, tid = threadIdx.x;
    const size_t rb = (size_t)t * HID_;
    float v0 = h[rb + tid], v1 = h[rb + tid + 256], v2 = h[rb + tid + 512];
    float sm = v0 + v1 + v2;
    float sq = v0 * v0 + v1 * v1 + v2 * v2;
#pragma unroll
    for (int off = 32; off > 0; off >>= 1) { sm += __shfl_xor(sm, off); sq += __shfl_xor(sq, off); }
    __shared__ float ws4[8];
    const int wid = tid >> 6, lane = tid & 63;
    if (lane == 0) { ws4[wid] = sm; ws4[4 + wid] = sq; }
    __syncthreads();
    sm = ws4[0] + ws4[1] + ws4[2] + ws4[3];
    sq = ws4[4] + ws4[5] + ws4[6] + ws4[7];
    const float mu = sm * (1.f / HID_);
    const float rs = rsqrtf(sq * (1.f / HID_) - mu * mu + 1e-6f);
    bf16_t* row = pre + (size_t)t * 1536;
#pragma unroll
    for (int k2 = 0; k2 < 3; ++k2) {
        const int c = tid + k2 * 256;
        const float v = (k2 == 0 ? v0 : k2 == 1 ? v1 : v2);
        float o = (v - mu) * rs * hw[c] + hbi[c] + __bfloat162float(xskip[rb + c]);
        const float rv = __bfloat162float(r[rb + c]);
        o *= rv * (1.f / (1.f + __expf(-rv)));
        bf16_t hh = __float2bfloat16(o);
        row[c] = hh;
        row[768 + c] = __float2bfloat16(o - __bfloat162float(hh));
    }
}

extern "C" void kernel_launch(void* const* d_in, const int* in_sizes, int n_in,
                              void* d_out, int out_size, void* d_ws, size_t ws_size,
                              hipStream_t stream) {
    const float* x      = (const float*)d_in[0];
    const float* ln_w   = (const float*)d_in[1];
    const float* ln_b   = (const float*)d_in[2];
    const float* up_l_w = (const float*)d_in[3];
    const float* up_r_w = (const float*)d_in[4];
    const float* conv_w = (const float*)d_in[5];
    const float* skip_w = (const float*)d_in[6];
    const float* fused_w= (const float*)d_in[7];
    const float* fused_b= (const float*)d_in[8];
    const float* hid_w  = (const float*)d_in[9];
    const float* hid_b  = (const float*)d_in[10];
    const float* down_w = (const float*)d_in[11];
    float* out = (float*)d_out;
    (void)n_in; (void)out_size; (void)ws_size;

    const size_t T = (size_t)in_sizes[0] / D_;   // 16384
    const int B = (int)(T / S_);                 // 8

    // ---- workspace layout: 231.9 MB total (proven-safe < 244 MB) ----
    char* ws = (char*)d_ws;
    size_t off = 0;
    auto take = [&](size_t b) -> char* {
        char* p = ws + off; off = (off + b + 255) & ~(size_t)255; return p;
    };
    bf16_t* wdn_h = (bf16_t*)take((size_t)D_ * HID_ * 2);
    bf16_t* wdn_l = (bf16_t*)take((size_t)D_ * HID_ * 2);
    bf16_t* wul_h = (bf16_t*)take((size_t)P_ * D_ * 2);
    bf16_t* wul_l = (bf16_t*)take((size_t)P_ * D_ * 2);
    bf16_t* wur   = (bf16_t*)take((size_t)HID_ * D_ * 2);
    bf16_t* wsk   = (bf16_t*)take((size_t)HID_ * P_ * 2);
    bf16_t* wfu_h = (bf16_t*)take((size_t)3072 * P_ * 2);
    bf16_t* wfu_l = (bf16_t*)take((size_t)3072 * P_ * 2);
    char*   xnreg = take(T * 1536 * 2);   // ln hi/lo -> compact xc-hi plane -> h fp32
    char*   big   = take(T * 1536 * 4);   // xl fp32 -> [o|q|k|v] bf16 -> pre hi/lo
    bf16_t* rbuf  = (bf16_t*)take(T * HID_ * 2);
    bf16_t* skipb = (bf16_t*)take(T * HID_ * 2);
    float*  gates = (float*)take(T * 16 * 4);

    bf16_t* xn   = (bf16_t*)xnreg;                       // [T,1536] pair rows
    bf16_t* xch  = (bf16_t*)xnreg;                       // compact xc-hi plane [T,1536]
    float*  h    = (float*)xnreg;                        // [T,768] fp32
    float*  xl   = (float*)big;                          // [T,1536] fp32
    bf16_t* obuf = (bf16_t*)big;                         // [T,768] bf16
    bf16_t* qbuf = (bf16_t*)(big + T * HID_ * 2);
    bf16_t* kbuf = (bf16_t*)(big + T * HID_ * 4);
    bf16_t* vbuf = (bf16_t*)(big + T * HID_ * 6);
    bf16_t* pre  = (bf16_t*)big;                         // [T,1536] pair rows (over o,q)

    // 1. weight conversions
    cvt2_kernel<<<512, 256, 0, stream>>>(down_w, wdn_h, wdn_l, D_ * HID_);
    cvt2_kernel<<<512, 256, 0, stream>>>(up_l_w, wul_h, wul_l, P_ * D_);
    cvt_kernel <<<512, 256, 0, stream>>>(up_r_w, wur, HID_ * D_);
    cvt_kernel <<<512, 256, 0, stream>>>(skip_w, wsk, HID_ * P_);
    cvt2_kernel<<<2048, 256, 0, stream>>>(fused_w + (size_t)16 * P_, wfu_h, wfu_l, 3072 * P_);
    // 2. LayerNorm -> xn hi/lo
    ln_x_kernel<<<(int)T, 256, 0, stream>>>(x, ln_w, ln_b, xn);
    // 3. xl = xn @ up_l^T (3-pass split, fp32 out)
    gemm_k<3, 1><<<dim3(P_ / 128, T / 128), 256, 0, stream>>>(
        (const char*)xn, 3072, 1536, wul_h, wul_l, D_,
        nullptr, xl, P_, nullptr, nullptr, nullptr, nullptr, nullptr);
    // 4. r = xn_hi @ up_r^T (1-pass)
    gemm_k<1, 0><<<dim3(HID_ / 128, T / 128), 256, 0, stream>>>(
        (const char*)xn, 3072, 0, wur, nullptr, D_,
        rbuf, nullptr, HID_, nullptr, nullptr, nullptr, nullptr, nullptr);
    // 5. conv+silu -> compact xc-hi plane (xn now dead); exact fp32 gates fused in
    conv_gate_kernel<<<(int)T, 192, 0, stream>>>(xl, conv_w, fused_w, fused_b, xch, gates);
    // 6. x_skip = xc_hi @ skip^T (1-pass)   [xl/big now dead]
    gemm_k<1, 0><<<dim3(HID_ / 128, T / 128), 256, 0, stream>>>(
        (const char*)xch, 3072, 0, wsk, nullptr, P_,
        skipb, nullptr, HID_, nullptr, nullptr, nullptr, nullptr, nullptr);
    // 7. o,q,k,v = xc_hi @ fused[16:]^T (2-pass: Wh + Wl; +bias, activations)
    gemm_k<2, 2><<<dim3(3072 / 128, T / 128), 256, 0, stream>>>(
        (const char*)xch, 3072, 0, wfu_h, wfu_l, P_,
        obuf, nullptr, 0, qbuf, kbuf, vbuf, fused_b + 16, nullptr);
    // 8. sequential recurrence -> h fp32 (over xc-hi, dead)
    recur_kernel<<<B * NH_, 384, 0, stream>>>(gates, qbuf, kbuf, vbuf, obuf, h);
    // 9. (LN(h)+skip)*silu(r) -> pre hi/lo (over o,q, dead)
    epi1_kernel<<<(int)T, 256, 0, stream>>>(h, skipb, rbuf, hid_w, hid_b, pre);
    // 10. out = pre @ down^T + x (3-pass split)
    gemm_k<3, 3><<<dim3(HID_ / 128, T / 128), 256, 0, stream>>>(
        (const char*)pre, 3072, 1536, wdn_h, wdn_l, HID_,
        nullptr, out, HID_, nullptr, nullptr, nullptr, nullptr, x);
}

// Round 4
// 1211.519 us; speedup vs baseline: 3.1042x; 3.1042x over previous
//
#include <hip/hip_runtime.h>
#include <hip/hip_bf16.h>

#define D_    768
#define P_    1536
#define HID_  768
#define NH_   8
#define DH_   96
#define S_    2048
#define LCH   256     // recurrence chunk length
#define NCH   8       // chunks per sequence

typedef __hip_bfloat16 bf16_t;
typedef __attribute__((ext_vector_type(8))) short s16x8;
typedef __attribute__((ext_vector_type(8))) unsigned short u16x8;
typedef __attribute__((ext_vector_type(4))) float f32x4;

__device__ __forceinline__ float b2f(unsigned short u) {
    union { unsigned int i; float f; } x; x.i = ((unsigned int)u) << 16; return x.f;
}
__device__ __forceinline__ unsigned short f2b(float f) {
    bf16_t h = __float2bfloat16(f);
    unsigned short u; __builtin_memcpy(&u, &h, 2); return u;
}
__device__ __forceinline__ bf16_t u2b(unsigned short u) {
    bf16_t t; __builtin_memcpy(&t, &u, 2); return t;
}

// async global->LDS, 16B per lane (LDS dest = wave-uniform base + lane*16, linear layout)
__device__ __forceinline__ void gload16(const void* g, const void* l) {
    __builtin_amdgcn_global_load_lds(
        (const __attribute__((address_space(1))) unsigned int*)(unsigned long long)(g),
        (__attribute__((address_space(3))) unsigned int*)(unsigned int)(unsigned long long)(l),
        16, 0, 0);
}

// ---------------- fp32 -> bf16 (single) ----------------
__global__ void cvt_kernel(const float* __restrict__ src, bf16_t* __restrict__ dst, int n) {
    int i = blockIdx.x * blockDim.x + threadIdx.x;
    int stride = gridDim.x * blockDim.x;
    for (; i < n; i += stride) dst[i] = __float2bfloat16(src[i]);
}

// ---------------- fp32 -> bf16 hi/lo split ----------------
__global__ void cvt2_kernel(const float* __restrict__ src, bf16_t* __restrict__ hi,
                            bf16_t* __restrict__ lo, int n) {
    int i = blockIdx.x * blockDim.x + threadIdx.x;
    int stride = gridDim.x * blockDim.x;
    for (; i < n; i += stride) {
        float x = src[i];
        bf16_t h = __float2bfloat16(x);
        hi[i] = h;
        lo[i] = __float2bfloat16(x - __bfloat162float(h));
    }
}

// ---------------- LayerNorm(x) -> bf16 hi/lo pair rows [hi 768 | lo 768] ----------------
__global__ __launch_bounds__(256) void ln_x_kernel(const float* __restrict__ x,
                                                   const float* __restrict__ w,
                                                   const float* __restrict__ b,
                                                   bf16_t* __restrict__ xn) {
    const int t = blockIdx.x, tid = threadIdx.x;
    const size_t rb = (size_t)t * D_;
    float v0 = x[rb + tid], v1 = x[rb + tid + 256], v2 = x[rb + tid + 512];
    float sm = v0 + v1 + v2;
    float sq = v0 * v0 + v1 * v1 + v2 * v2;
#pragma unroll
    for (int off = 32; off > 0; off >>= 1) { sm += __shfl_xor(sm, off); sq += __shfl_xor(sq, off); }
    __shared__ float ws4[8];
    const int wid = tid >> 6, lane = tid & 63;
    if (lane == 0) { ws4[wid] = sm; ws4[4 + wid] = sq; }
    __syncthreads();
    sm = ws4[0] + ws4[1] + ws4[2] + ws4[3];
    sq = ws4[4] + ws4[5] + ws4[6] + ws4[7];
    const float mu = sm * (1.f / D_);
    const float rs = rsqrtf(sq * (1.f / D_) - mu * mu + 1e-6f);
    bf16_t* row = xn + (size_t)t * 1536;
#pragma unroll
    for (int k2 = 0; k2 < 3; ++k2) {
        const int c = tid + k2 * 256;
        const float v = (k2 == 0 ? v0 : k2 == 1 ? v1 : v2);
        const float y = (v - mu) * rs * w[c] + b[c];
        bf16_t h = __float2bfloat16(y);
        row[c] = h;
        row[768 + c] = __float2bfloat16(y - __bfloat162float(h));
    }
}

// ---------------- conv(K=4)+SiLU from fp32 xl; writes compact xc-hi plane; fp32 gates fused ----------------
__global__ __launch_bounds__(192) void conv_gate_kernel(const float* __restrict__ xl,
                                                        const float* __restrict__ cw,
                                                        const float* __restrict__ fw,
                                                        const float* __restrict__ fb,
                                                        bf16_t* __restrict__ xch,
                                                        float* __restrict__ gates) {
    const int t = blockIdx.x, c = threadIdx.x;   // c: 8-float chunk, 192*8 = 1536
    const float* row = xl + (size_t)t * P_;
    const float4* r4 = (const float4*)row;
    float4 a = r4[2 * c], b4 = r4[2 * c + 1];
    float pm3 = 0.f, pm2 = 0.f, pm1 = 0.f;
    if (c > 0) { pm3 = row[c * 8 - 3]; pm2 = row[c * 8 - 2]; pm1 = row[c * 8 - 1]; }
    const float w0 = cw[0], w1 = cw[1], w2 = cw[2], w3 = cw[3];
    float xv[11] = {pm3, pm2, pm1, a.x, a.y, a.z, a.w, b4.x, b4.y, b4.z, b4.w};
    float xc[8];
    u16x8 h8;
#pragma unroll
    for (int j = 0; j < 8; ++j) {
        float s = w0 * xv[j] + w1 * xv[j + 1] + w2 * xv[j + 2] + w3 * xv[j + 3];
        s = s * (1.f / (1.f + __expf(-s)));   // SiLU
        xc[j] = s;
        h8[j] = f2b(s);
    }
    *(u16x8*)(xch + (size_t)t * P_ + c * 8) = h8;

    // fused exact-fp32 gate dots: z_j = sum_p xc_p * fw[j*1536+p], j = 0..15
    float pj[16];
#pragma unroll
    for (int j = 0; j < 16; ++j) {
        const float* wr = fw + (size_t)j * P_ + c * 8;
        float p = 0.f;
#pragma unroll
        for (int u = 0; u < 8; ++u) p += xc[u] * wr[u];
        pj[j] = p;
    }
#pragma unroll
    for (int j = 0; j < 16; ++j)
#pragma unroll
        for (int off = 32; off > 0; off >>= 1) pj[j] += __shfl_xor(pj[j], off);
    __shared__ float red[3][16];
    const int wv = c >> 6, ln = c & 63;
    if (ln == 0) {
#pragma unroll
        for (int j = 0; j < 16; ++j) red[wv][j] = pj[j];
    }
    __syncthreads();
    if (c < 16) {
        const float z = red[0][c] + red[1][c] + red[2][c] + fb[c];
        gates[(size_t)t * 16 + c] = 15.f * tanhf(z * (1.f / 15.f));
    }
}

// ---------------- 128x128 bf16 MFMA GEMM, C = A[M,K] * W[N,K]^T, multi-pass split ----------------
// pass 0: Ah*Wh; pass 1: Ah*Wl; pass 2: (A+aloff)*Wh.
template <int NPASS, int MODE>
__global__ __launch_bounds__(256) void gemm_k(
    const char* __restrict__ Ab, int astride, int aloff,
    const bf16_t* __restrict__ Wh, const bf16_t* __restrict__ Wl, int K,
    bf16_t* __restrict__ out0, float* __restrict__ outf, int ldout,
    bf16_t* __restrict__ oq, bf16_t* __restrict__ ok, bf16_t* __restrict__ ov,
    const float* __restrict__ bias, const float* __restrict__ resid) {
    __shared__ bf16_t smA[128 * 64];
    __shared__ bf16_t smB[128 * 64];
    const int tid = threadIdx.x;
    const int mt = blockIdx.y, nt = blockIdx.x;
    const int wid = tid >> 6, lane = tid & 63;
    const int wm = wid >> 1, wn = wid & 1;
    const int l15 = lane & 15, l4 = lane >> 4;

    f32x4 acc[4][4];
#pragma unroll
    for (int i = 0; i < 4; ++i)
#pragma unroll
        for (int j = 0; j < 4; ++j) acc[i][j] = f32x4{0.f, 0.f, 0.f, 0.f};

    const int trow = tid >> 3;   // 0..31
    const int tcc = tid & 7;
    const int KT = K >> 6;

    for (int pass = 0; pass < NPASS; ++pass) {
        const char* ap = Ab + (pass == 2 ? aloff : 0);
        const bf16_t* wp = (pass == 1) ? Wl : Wh;
        for (int kt = 0; kt < KT; ++kt) {
            const int k0 = kt << 6;
            __syncthreads();
#pragma unroll
            for (int rr = 0; rr < 4; ++rr) {
                const int row = rr * 32 + trow;
                const int loff = (rr * 256 + tid) * 16;
                gload16(ap + (size_t)(mt * 128 + row) * astride + (size_t)(k0 + tcc * 8) * 2,
                        (const char*)smA + loff);
                gload16((const char*)wp + ((size_t)(nt * 128 + row) * K + k0 + tcc * 8) * 2,
                        (const char*)smB + loff);
            }
            __syncthreads();
#pragma unroll
            for (int kk = 0; kk < 2; ++kk) {
                s16x8 af[4], bfr[4];
#pragma unroll
                for (int i = 0; i < 4; ++i) {
                    const int ar = wm * 64 + i * 16 + l15;
                    af[i] = *(const s16x8*)((const char*)smA + ar * 128 + kk * 64 + l4 * 16);
                    const int br = wn * 64 + i * 16 + l15;
                    bfr[i] = *(const s16x8*)((const char*)smB + br * 128 + kk * 64 + l4 * 16);
                }
#pragma unroll
                for (int i = 0; i < 4; ++i)
#pragma unroll
                    for (int j = 0; j < 4; ++j)
                        acc[i][j] = __builtin_amdgcn_mfma_f32_16x16x32_bf16(af[i], bfr[j], acc[i][j], 0, 0, 0);
            }
        }
    }

    const int grow0 = mt * 128 + wm * 64;
    const int gcol0 = nt * 128 + wn * 64;
#pragma unroll
    for (int i = 0; i < 4; ++i) {
#pragma unroll
        for (int j = 0; j < 4; ++j) {
            const int gcol = gcol0 + j * 16 + l15;
#pragma unroll
            for (int r = 0; r < 4; ++r) {
                const int grow = grow0 + i * 16 + l4 * 4 + r;
                float v = acc[i][j][r];
                if constexpr (MODE == 0) {
                    out0[(size_t)grow * ldout + gcol] = __float2bfloat16(v);
                } else if constexpr (MODE == 1) {
                    outf[(size_t)grow * ldout + gcol] = v;
                } else if constexpr (MODE == 2) {
                    v += bias[gcol];
                    const int seg = gcol / 768;          // uniform per block (768 % 128 == 0)
                    const int col = gcol - seg * 768;
                    const size_t oo = (size_t)grow * 768 + col;
                    if (seg == 0)      out0[oo] = __float2bfloat16(1.f / (1.f + __expf(-v)));
                    else if (seg == 1) oq[oo] = __float2bfloat16(v);
                    else if (seg == 2) ok[oo] = __float2bfloat16(v * 0.10206207261596577f); // 1/sqrt(96)
                    else               ov[oo] = __float2bfloat16(v);
                } else {
                    const size_t oo = (size_t)grow * ldout + gcol;
                    outf[oo] = v + resid[oo];
                }
            }
        }
    }
}

// ================= chunkwise-parallel mLSTM recurrence =================
// m_t = max(f_t + m_{t-1}, i_t); F_t = within-chunk cumsum(f) (inclusive)
// wA_t = i_t - F_t ; g_t = F_t - m_t ; per chunk: m_prev, alpha = exp(m_prev + F_tot - m_end)
// state update:  C_t = exp(m_prev+g_t) C_start + sum_{s<=t} exp(wA_s+g_t) v_s k_s^T

// ---- 1. gate scan: 1 block per batch b, 64 threads = 8 heads x 8 chunks ----
__global__ __launch_bounds__(64) void mscan_kernel(const float* __restrict__ gates,
                                                   float* __restrict__ wAo, float* __restrict__ go,
                                                   float* __restrict__ mprev, float* __restrict__ alpha) {
    const int b = blockIdx.x;
    const int lane = threadIdx.x;
    const int hd = lane >> 3, c = lane & 7;
    const size_t gbase = ((size_t)b * S_ + c * LCH) * 16;
    float F = 0.f, I = -1e30f;
    for (int t = 0; t < LCH; ++t) {
        const float fi = gates[gbase + t * 16 + hd];
        const float ff = gates[gbase + t * 16 + 8 + hd];
        I = fmaxf(I + ff, fi);
        F += ff;
    }
    // segmented (8-lane) inclusive scan with compose (F1,I1)∘(F2,I2) = (F1+F2, max(I1+F2, I2))
    float Fs = F, Is = I;
#pragma unroll
    for (int off = 1; off < 8; off <<= 1) {
        const float Fo = __shfl_up(Fs, off);
        const float Io = __shfl_up(Is, off);
        if (c >= off) { Is = fmaxf(Io + Fs, Is); Fs = Fo + Fs; }
    }
    const float Fe = __shfl_up(Fs, 1);
    const float Ie = __shfl_up(Is, 1);
    const float mp = (c == 0) ? 0.f : fmaxf(Fe, Ie);   // m at chunk start (m_{-1}=0)
    float m = mp; F = 0.f;
    const size_t wbase = ((size_t)(b * NH_ + hd)) * S_ + c * LCH;
    for (int t = 0; t < LCH; ++t) {
        const float fi = gates[gbase + t * 16 + hd];
        const float ff = gates[gbase + t * 16 + 8 + hd];
        F += ff;
        m = fmaxf(ff + m, fi);
        wAo[wbase + t] = fi - F;
        go[wbase + t] = F - m;
    }
    const int idx = (b * NH_ + hd) * NCH + c;
    mprev[idx] = mp;
    alpha[idx] = __expf(fminf(mp + F - m, 0.f));
}

// ---- 2. chunk summaries: B_c = sum coeff_s v_s k_s^T ; nB_c = sum coeff_s k_s ----
__global__ __launch_bounds__(512) void chunkA_kernel(
    const bf16_t* __restrict__ kb, const bf16_t* __restrict__ vb,
    const float* __restrict__ wAo, const float* __restrict__ go,
    float* __restrict__ Bst) {
    const int c = blockIdx.x, bh = blockIdx.y;
    const int b = bh >> 3, hd = bh & 7;
    __shared__ bf16_t kT[96 * 136];     // [e][sigma'] 26112B
    __shared__ bf16_t vTh[96 * 136];
    __shared__ bf16_t vTl[96 * 136];
    __shared__ float coeffL[128];
    const int tid = threadIdx.x, lane = tid & 63, wid = tid >> 6;
    const int l15 = lane & 15, l4 = lane >> 4;
    const int s0 = c * LCH;
    const size_t seqb = (size_t)bh * S_;
    const float gend = go[seqb + s0 + LCH - 1];
    f32x4 acc[6];
#pragma unroll
    for (int nf = 0; nf < 6; ++nf) acc[nf] = f32x4{0.f, 0.f, 0.f, 0.f};
    float nacc = 0.f;
    const int ne = tid - 384;    // waves 6,7 compute nB

    for (int sb = 0; sb < 2; ++sb) {          // 2 sigma-tiles of 128
        __syncthreads();
        if (tid < 128) coeffL[tid] = __expf(fminf(wAo[seqb + s0 + sb * 128 + tid] + gend, 0.f));
        __syncthreads();
        {   // stage kT + coeff-scaled v hi/lo (transposed)
            const int st = tid >> 2, e0 = (tid & 3) * 24;
            const size_t rowb = (size_t)(b * S_ + s0 + sb * 128 + st) * HID_ + hd * DH_ + e0;
            const float cf = coeffL[st];
#pragma unroll
            for (int jj = 0; jj < 3; ++jj) {
                const u16x8 kv = *(const u16x8*)(kb + rowb + jj * 8);
                const u16x8 vv = *(const u16x8*)(vb + rowb + jj * 8);
#pragma unroll
                for (int u = 0; u < 8; ++u) {
                    const int e = e0 + jj * 8 + u;
                    kT[e * 136 + st] = u2b(kv[u]);
                    const float vf = b2f(vv[u]) * cf;
                    const bf16_t hh = __float2bfloat16(vf);
                    vTh[e * 136 + st] = hh;
                    vTl[e * 136 + st] = __float2bfloat16(vf - __bfloat162float(hh));
                }
            }
        }
        __syncthreads();
        if (wid < 6) {
#pragma unroll
            for (int pass = 0; pass < 2; ++pass) {
                const bf16_t* Ap = pass ? vTl : vTh;
#pragma unroll
                for (int ks = 0; ks < 4; ++ks) {
                    const s16x8 af = *(const s16x8*)((const char*)Ap + (wid * 16 + l15) * 272 + ks * 64 + l4 * 16);
#pragma unroll
                    for (int nf = 0; nf < 6; ++nf) {
                        const s16x8 bf = *(const s16x8*)((const char*)kT + (nf * 16 + l15) * 272 + ks * 64 + l4 * 16);
                        acc[nf] = __builtin_amdgcn_mfma_f32_16x16x32_bf16(af, bf, acc[nf], 0, 0, 0);
                    }
                }
            }
        } else if (ne < 96) {
            for (int sg = 0; sg < 128; ++sg)
                nacc += coeffL[sg] * __bfloat162float(kT[ne * 136 + sg]);
        }
    }
    float* outp = Bst + ((size_t)bh * NCH + c) * 9312;
    if (wid < 6) {
#pragma unroll
        for (int nf = 0; nf < 6; ++nf)
#pragma unroll
            for (int r = 0; r < 4; ++r)
                outp[(size_t)(wid * 16 + l4 * 4 + r) * 96 + nf * 16 + l15] = acc[nf][r];
    } else if (ne < 96) {
        outp[9216 + ne] = nacc;
    }
}

// ---- 3. inter-chunk scan, in-place: slot c becomes state BEFORE chunk c ----
__global__ __launch_bounds__(96) void chunkB_kernel(float* __restrict__ Bst,
                                                    const float* __restrict__ alpha) {
    const int idx = blockIdx.x * 96 + threadIdx.x;   // 0..9311
    const int bh = blockIdx.y;
    float val = (idx < 9216) ? 0.f : 1.f;            // C0 = 0, n0 = ones
    for (int c = 0; c < NCH; ++c) {
        float* p = Bst + ((size_t)bh * NCH + c) * 9312 + idx;
        const float t = *p;
        *p = val;
        val = alpha[bh * NCH + c] * val + t;
    }
}

// ---- 4. outputs: h = o * (inter + intra)/max(den,1), 64 q-rows per block ----
__global__ __launch_bounds__(256) void chunkC_kernel(
    const bf16_t* __restrict__ qb, const bf16_t* __restrict__ kb,
    const bf16_t* __restrict__ vb, const bf16_t* __restrict__ ob,
    const float* __restrict__ wAo, const float* __restrict__ go,
    const float* __restrict__ mprev, const float* __restrict__ Cst,
    float* __restrict__ hb) {
    const int c = blockIdx.x >> 2, qblk = blockIdx.x & 3;
    const int bh = blockIdx.y, b = bh >> 3, hd = bh & 7;
    __shared__ bf16_t Qs[64 * 104];
    __shared__ bf16_t Ks[64 * 104];
    __shared__ bf16_t vTs[112 * 72];      // rows 0..95 = V^T tile, row 96 = ones (den), 97..111 = 0
    __shared__ bf16_t Phs[64 * 72];
    __shared__ bf16_t Pls[64 * 72];
    __shared__ bf16_t CsH[112 * 104];     // rows 0..95 = C_start, row 96 = n_start, 97..111 = 0
    __shared__ bf16_t CsL[112 * 104];
    __shared__ float wAL[256];
    __shared__ float gL[64];
    __shared__ float scL[64];
    const int tid = threadIdx.x, lane = tid & 63, wid = tid >> 6;
    const int l15 = lane & 15, l4 = lane >> 4;
    const int s0 = c * LCH;
    const size_t seqb = (size_t)bh * S_;
    const int tq0 = b * S_ + s0 + qblk * 64;

    wAL[tid] = wAo[seqb + s0 + tid];
    if (tid < 64) {
        const float gg = go[seqb + s0 + qblk * 64 + tid];
        gL[tid] = gg;
        scL[tid] = __expf(fminf(mprev[bh * NCH + c] + gg, 0.f));
    }
    {   // Q stage
        const int tt = tid >> 2, e0 = (tid & 3) * 24;
        const bf16_t* qrow = qb + (size_t)(tq0 + tt) * HID_ + hd * DH_ + e0;
#pragma unroll
        for (int jj = 0; jj < 3; ++jj)
            *(u16x8*)&Qs[tt * 104 + e0 + jj * 8] = *(const u16x8*)(qrow + jj * 8);
    }
    {   // chunk-start state hi/lo + pads
        const float* Csp = Cst + ((size_t)bh * NCH + c) * 9312;
        for (int i = tid; i < 9312; i += 256) {
            int dd, ee;
            if (i < 9216) { dd = i / 96; ee = i - dd * 96; }
            else          { dd = 96;     ee = i - 9216; }
            const float xv = Csp[i];
            const bf16_t hh = __float2bfloat16(xv);
            CsH[dd * 104 + ee] = hh;
            CsL[dd * 104 + ee] = __float2bfloat16(xv - __bfloat162float(hh));
        }
        const bf16_t z16 = __float2bfloat16(0.f);
        for (int i = tid; i < 15 * 104; i += 256) { CsH[97 * 104 + i] = z16; CsL[97 * 104 + i] = z16; }
        if (tid < 64) vTs[96 * 72 + tid] = __float2bfloat16(1.f);
        for (int i = tid; i < 15 * 72; i += 256) vTs[97 * 72 + i] = z16;
    }
    __syncthreads();

    // inter: acc = Q @ CsE^T (2-pass hi/lo), then scale rows by exp(m_prev + g_tau)
    f32x4 acc[7];
#pragma unroll
    for (int nf = 0; nf < 7; ++nf) acc[nf] = f32x4{0.f, 0.f, 0.f, 0.f};
#pragma unroll
    for (int pass = 0; pass < 2; ++pass) {
        const bf16_t* Cp = pass ? CsL : CsH;
#pragma unroll
        for (int ks = 0; ks < 3; ++ks) {
            const s16x8 af = *(const s16x8*)((const char*)Qs + (wid * 16 + l15) * 208 + ks * 64 + l4 * 16);
#pragma unroll
            for (int nf = 0; nf < 7; ++nf) {
                const s16x8 bf = *(const s16x8*)((const char*)Cp + (nf * 16 + l15) * 208 + ks * 64 + l4 * 16);
                acc[nf] = __builtin_amdgcn_mfma_f32_16x16x32_bf16(af, bf, acc[nf], 0, 0, 0);
            }
        }
    }
    {
        float scr[4];
#pragma unroll
        for (int r = 0; r < 4; ++r) scr[r] = scL[wid * 16 + l4 * 4 + r];
#pragma unroll
        for (int nf = 0; nf < 7; ++nf)
#pragma unroll
            for (int r = 0; r < 4; ++r) acc[nf][r] *= scr[r];
    }

    // intra: sigma-tiles of 64 up to (and including, masked) the diagonal tile
    for (int sb = 0; sb <= qblk; ++sb) {
        __syncthreads();
        {   // stage K tile rows + V tile transposed
            const int tt = tid >> 2, e0 = (tid & 3) * 24;
            const size_t rowb = (size_t)(b * S_ + s0 + sb * 64 + tt) * HID_ + hd * DH_ + e0;
#pragma unroll
            for (int jj = 0; jj < 3; ++jj) {
                *(u16x8*)&Ks[tt * 104 + e0 + jj * 8] = *(const u16x8*)(kb + rowb + jj * 8);
                const u16x8 vv = *(const u16x8*)(vb + rowb + jj * 8);
#pragma unroll
                for (int u = 0; u < 8; ++u)
                    vTs[(e0 + jj * 8 + u) * 72 + tt] = u2b(vv[u]);
            }
        }
        __syncthreads();
        f32x4 pacc[4];
#pragma unroll
        for (int nf = 0; nf < 4; ++nf) pacc[nf] = f32x4{0.f, 0.f, 0.f, 0.f};
#pragma unroll
        for (int ks = 0; ks < 3; ++ks) {
            const s16x8 af = *(const s16x8*)((const char*)Qs + (wid * 16 + l15) * 208 + ks * 64 + l4 * 16);
#pragma unroll
            for (int nf = 0; nf < 4; ++nf) {
                const s16x8 bf = *(const s16x8*)((const char*)Ks + (nf * 16 + l15) * 208 + ks * 64 + l4 * 16);
                pacc[nf] = __builtin_amdgcn_mfma_f32_16x16x32_bf16(af, bf, pacc[nf], 0, 0, 0);
            }
        }
        // weight + causal mask, split hi/lo into LDS
#pragma unroll
        for (int nf = 0; nf < 4; ++nf) {
#pragma unroll
            for (int r = 0; r < 4; ++r) {
                const int tr = wid * 16 + l4 * 4 + r;
                const int sg = nf * 16 + l15;
                float p = 0.f;
                if (sb < qblk || sg <= tr)
                    p = pacc[nf][r] * __expf(fminf(wAL[sb * 64 + sg] + gL[tr], 0.f));
                const bf16_t hh = __float2bfloat16(p);
                Phs[tr * 72 + sg] = hh;
                Pls[tr * 72 + sg] = __float2bfloat16(p - __bfloat162float(hh));
            }
        }
        __syncthreads();
#pragma unroll
        for (int pass = 0; pass < 2; ++pass) {
            const bf16_t* Pp = pass ? Pls : Phs;
#pragma unroll
            for (int ks = 0; ks < 2; ++ks) {
                const s16x8 af = *(const s16x8*)((const char*)Pp + (wid * 16 + l15) * 144 + ks * 64 + l4 * 16);
#pragma unroll
                for (int nf = 0; nf < 7; ++nf) {
                    const s16x8 bf = *(const s16x8*)((const char*)vTs + (nf * 16 + l15) * 144 + ks * 64 + l4 * 16);
                    acc[nf] = __builtin_amdgcn_mfma_f32_16x16x32_bf16(af, bf, acc[nf], 0, 0, 0);
                }
            }
        }
    }

    // write h = o * num / max(den,1); den rides in channel 96 (acc[6], l15==0)
#pragma unroll
    for (int r = 0; r < 4; ++r) {
        float den = __shfl(acc[6][r], lane & 48);
        den = fmaxf(den, 1.0f);
        const int tr = wid * 16 + l4 * 4 + r;
        const size_t rowb = (size_t)(tq0 + tr) * HID_ + hd * DH_;
#pragma unroll
        for (int nf = 0; nf < 6; ++nf) {
            const int dc = nf * 16 + l15;
            const float o = __bfloat162float(ob[rowb + dc]);
            hb[rowb + dc] = o * acc[nf][r] / den;
        }
    }
}

// ---------------- (LN(h)+skip)*silu(r) -> pre hi/lo pair rows ----------------
__global__ __launch_bounds__(256) void epi1_kernel(const float* __restrict__ h,
                                                   const bf16_t* __restrict__ xskip,
                                                   const bf16_t* __restrict__ r,
                                                   const float* __restrict__ hw,
                                                   const float* __restrict__ hbi,
                                                   bf16_t* __restrict__ pre) {
    const int t = blockIdx.x, tid = threadIdx.x;
    const size_t rb = (size_t)t * HID_;
    float v0 = h[rb + tid], v1 = h[rb + tid + 256], v2 = h[rb + tid + 512];
    float sm = v0 + v1 + v2;
    float sq = v0 * v0 + v1 * v1 + v2 * v2;
#pragma unroll
    for (int off = 32; off > 0; off >>= 1) { sm += __shfl_xor(sm, off); sq += __shfl_xor(sq, off); }
    __shared__ float ws4[8];
    const int wid = tid >> 6, lane = tid & 63;
    if (lane == 0) { ws4[wid] = sm; ws4[4 + wid] = sq; }
    __syncthreads();
    sm = ws4[0] + ws4[1] + ws4[2] + ws4[3];
    sq = ws4[4] + ws4[5] + ws4[6] + ws4[7];
    const float mu = sm * (1.f / HID_);
    const float rs = rsqrtf(sq * (1.f / HID_) - mu * mu + 1e-6f);
    bf16_t* row = pre + (size_t)t * 1536;
#pragma unroll
    for (int k2 = 0; k2 < 3; ++k2) {
        const int c = tid + k2 * 256;
        const float v = (k2 == 0 ? v0 : k2 == 1 ? v1 : v2);
        float o = (v - mu) * rs * hw[c] + hbi[c] + __bfloat162float(xskip[rb + c]);
        const float rv = __bfloat162float(r[rb + c]);
        o *= rv * (1.f / (1.f + __expf(-rv)));
        bf16_t hh = __float2bfloat16(o);
        row[c] = hh;
        row[768 + c] = __float2bfloat16(o - __bfloat162float(hh));
    }
}

extern "C" void kernel_launch(void* const* d_in, const int* in_sizes, int n_in,
                              void* d_out, int out_size, void* d_ws, size_t ws_size,
                              hipStream_t stream) {
    const float* x      = (const float*)d_in[0];
    const float* ln_w   = (const float*)d_in[1];
    const float* ln_b   = (const float*)d_in[2];
    const float* up_l_w = (const float*)d_in[3];
    const float* up_r_w = (const float*)d_in[4];
    const float* conv_w = (const float*)d_in[5];
    const float* skip_w = (const float*)d_in[6];
    const float* fused_w= (const float*)d_in[7];
    const float* fused_b= (const float*)d_in[8];
    const float* hid_w  = (const float*)d_in[9];
    const float* hid_b  = (const float*)d_in[10];
    const float* down_w = (const float*)d_in[11];
    float* out = (float*)d_out;
    (void)n_in; (void)out_size; (void)ws_size;

    const size_t T = (size_t)in_sizes[0] / D_;   // 16384
    const int B = (int)(T / S_);                 // 8

    // ---- workspace layout: 231.9 MB total (proven-safe, same as round 3) ----
    char* ws = (char*)d_ws;
    size_t off = 0;
    auto take = [&](size_t bytes) -> char* {
        char* p = ws + off; off = (off + bytes + 255) & ~(size_t)255; return p;
    };
    // pool weights first (all dead after fused GEMM) -> recurrence scratch aliases [0, 27.1MB)
    bf16_t* wul_h = (bf16_t*)take((size_t)P_ * D_ * 2);      // @0
    bf16_t* wul_l = (bf16_t*)take((size_t)P_ * D_ * 2);
    bf16_t* wur   = (bf16_t*)take((size_t)HID_ * D_ * 2);
    bf16_t* wsk   = (bf16_t*)take((size_t)HID_ * P_ * 2);
    bf16_t* wfu_h = (bf16_t*)take((size_t)3072 * P_ * 2);
    bf16_t* wfu_l = (bf16_t*)take((size_t)3072 * P_ * 2);    // pool ends @27,131,904
    bf16_t* wdn_h = (bf16_t*)take((size_t)D_ * HID_ * 2);    // alive till the end
    bf16_t* wdn_l = (bf16_t*)take((size_t)D_ * HID_ * 2);
    char*   xnreg = take(T * 1536 * 2);   // ln hi/lo -> compact xc-hi plane -> h fp32
    char*   big   = take(T * 1536 * 4);   // xl fp32 -> [o|q|k|v] bf16 -> pre hi/lo
    bf16_t* rbuf  = (bf16_t*)take(T * HID_ * 2);
    bf16_t* skipb = (bf16_t*)take(T * HID_ * 2);
    float*  gates = (float*)take(T * 16 * 4);

    bf16_t* xn   = (bf16_t*)xnreg;
    bf16_t* xch  = (bf16_t*)xnreg;
    float*  h    = (float*)xnreg;
    float*  xl   = (float*)big;
    bf16_t* obuf = (bf16_t*)big;
    bf16_t* qbuf = (bf16_t*)(big + T * HID_ * 2);
    bf16_t* kbuf = (bf16_t*)(big + T * HID_ * 4);
    bf16_t* vbuf = (bf16_t*)(big + T * HID_ * 6);
    bf16_t* pre  = (bf16_t*)big;

    // recurrence scratch aliased over the dead weight pool [0, 27.1MB)
    float* Bst    = (float*)ws;                         // 64*8*9312*4 = 19,070,976 B
    float* wAarr  = (float*)(ws + 19071232);            // 524,288 B
    float* garr   = (float*)(ws + 19595520);            // 524,288 B
    float* mprevA = (float*)(ws + 20119808);            // 2,048 B
    float* alphaA = (float*)(ws + 20121856);            // 2,048 B  (end 20.1MB < 27.1MB)

    // 1. weight conversions
    cvt2_kernel<<<512, 256, 0, stream>>>(up_l_w, wul_h, wul_l, P_ * D_);
    cvt_kernel <<<512, 256, 0, stream>>>(up_r_w, wur, HID_ * D_);
    cvt_kernel <<<512, 256, 0, stream>>>(skip_w, wsk, HID_ * P_);
    cvt2_kernel<<<2048, 256, 0, stream>>>(fused_w + (size_t)16 * P_, wfu_h, wfu_l, 3072 * P_);
    cvt2_kernel<<<512, 256, 0, stream>>>(down_w, wdn_h, wdn_l, D_ * HID_);
    // 2. LayerNorm -> xn hi/lo
    ln_x_kernel<<<(int)T, 256, 0, stream>>>(x, ln_w, ln_b, xn);
    // 3. xl = xn @ up_l^T (3-pass split, fp32 out)
    gemm_k<3, 1><<<dim3(P_ / 128, T / 128), 256, 0, stream>>>(
        (const char*)xn, 3072, 1536, wul_h, wul_l, D_,
        nullptr, xl, P_, nullptr, nullptr, nullptr, nullptr, nullptr);
    // 4. r = xn_hi @ up_r^T (1-pass)
    gemm_k<1, 0><<<dim3(HID_ / 128, T / 128), 256, 0, stream>>>(
        (const char*)xn, 3072, 0, wur, nullptr, D_,
        rbuf, nullptr, HID_, nullptr, nullptr, nullptr, nullptr, nullptr);
    // 5. conv+silu -> compact xc-hi plane (xn now dead); exact fp32 gates fused in
    conv_gate_kernel<<<(int)T, 192, 0, stream>>>(xl, conv_w, fused_w, fused_b, xch, gates);
    // 6. x_skip = xc_hi @ skip^T (1-pass)
    gemm_k<1, 0><<<dim3(HID_ / 128, T / 128), 256, 0, stream>>>(
        (const char*)xch, 3072, 0, wsk, nullptr, P_,
        skipb, nullptr, HID_, nullptr, nullptr, nullptr, nullptr, nullptr);
    // 7. o,q,k,v = xc_hi @ fused[16:]^T (2-pass; +bias, activations)
    gemm_k<2, 2><<<dim3(3072 / 128, T / 128), 256, 0, stream>>>(
        (const char*)xch, 3072, 0, wfu_h, wfu_l, P_,
        obuf, nullptr, 0, qbuf, kbuf, vbuf, fused_b + 16, nullptr);
    // 8. chunkwise-parallel recurrence -> h fp32 (weights in pool are dead now)
    mscan_kernel<<<B, 64, 0, stream>>>(gates, wAarr, garr, mprevA, alphaA);
    chunkA_kernel<<<dim3(NCH, B * NH_), 512, 0, stream>>>(kbuf, vbuf, wAarr, garr, Bst);
    chunkB_kernel<<<dim3(97, B * NH_), 96, 0, stream>>>(Bst, alphaA);
    chunkC_kernel<<<dim3(NCH * 4, B * NH_), 256, 0, stream>>>(qbuf, kbuf, vbuf, obuf,
                                                              wAarr, garr, mprevA, Bst, h);
    // 9. (LN(h)+skip)*silu(r) -> pre hi/lo (over o,q, dead)
    epi1_kernel<<<(int)T, 256, 0, stream>>>(h, skipb, rbuf, hid_w, hid_b, pre);
    // 10. out = pre @ down^T + x (3-pass split)
    gemm_k<3, 3><<<dim3(HID_ / 128, T / 128), 256, 0, stream>>>(
        (const char*)pre, 3072, 1536, wdn_h, wdn_l, HID_,
        nullptr, out, HID_, nullptr, nullptr, nullptr, nullptr, x);
}

// Round 5
// 938.003 us; speedup vs baseline: 4.0094x; 1.2916x over previous
//
#include <hip/hip_runtime.h>
#include <hip/hip_bf16.h>

#define D_    768
#define P_    1536
#define HID_  768
#define NH_   8
#define DH_   96
#define S_    2048
#define LCH   256     // recurrence chunk length
#define NCH   8       // chunks per sequence

typedef __hip_bfloat16 bf16_t;
typedef __attribute__((ext_vector_type(8))) short s16x8;
typedef __attribute__((ext_vector_type(8))) unsigned short u16x8;
typedef __attribute__((ext_vector_type(4))) float f32x4;

__device__ __forceinline__ float b2f(unsigned short u) {
    union { unsigned int i; float f; } x; x.i = ((unsigned int)u) << 16; return x.f;
}
__device__ __forceinline__ unsigned short f2b(float f) {
    bf16_t h = __float2bfloat16(f);
    unsigned short u; __builtin_memcpy(&u, &h, 2); return u;
}
__device__ __forceinline__ bf16_t u2b(unsigned short u) {
    bf16_t t; __builtin_memcpy(&t, &u, 2); return t;
}

// async global->LDS, 16B per lane (LDS dest = wave-uniform base + lane*16, linear layout)
__device__ __forceinline__ void gload16(const void* g, const void* l) {
    __builtin_amdgcn_global_load_lds(
        (const __attribute__((address_space(1))) unsigned int*)(unsigned long long)(g),
        (__attribute__((address_space(3))) unsigned int*)(unsigned int)(unsigned long long)(l),
        16, 0, 0);
}

// ---------------- fp32 -> bf16 (single) ----------------
__global__ void cvt_kernel(const float* __restrict__ src, bf16_t* __restrict__ dst, int n) {
    int i = blockIdx.x * blockDim.x + threadIdx.x;
    int stride = gridDim.x * blockDim.x;
    for (; i < n; i += stride) dst[i] = __float2bfloat16(src[i]);
}

// ---------------- fp32 -> bf16 hi/lo split ----------------
__global__ void cvt2_kernel(const float* __restrict__ src, bf16_t* __restrict__ hi,
                            bf16_t* __restrict__ lo, int n) {
    int i = blockIdx.x * blockDim.x + threadIdx.x;
    int stride = gridDim.x * blockDim.x;
    for (; i < n; i += stride) {
        float x = src[i];
        bf16_t h = __float2bfloat16(x);
        hi[i] = h;
        lo[i] = __float2bfloat16(x - __bfloat162float(h));
    }
}

// ---------------- LayerNorm(x) -> bf16 hi/lo pair rows [hi 768 | lo 768] ----------------
__global__ __launch_bounds__(256) void ln_x_kernel(const float* __restrict__ x,
                                                   const float* __restrict__ w,
                                                   const float* __restrict__ b,
                                                   bf16_t* __restrict__ xn) {
    const int t = blockIdx.x, tid = threadIdx.x;
    const size_t rb = (size_t)t * D_;
    float v0 = x[rb + tid], v1 = x[rb + tid + 256], v2 = x[rb + tid + 512];
    float sm = v0 + v1 + v2;
    float sq = v0 * v0 + v1 * v1 + v2 * v2;
#pragma unroll
    for (int off = 32; off > 0; off >>= 1) { sm += __shfl_xor(sm, off); sq += __shfl_xor(sq, off); }
    __shared__ float ws4[8];
    const int wid = tid >> 6, lane = tid & 63;
    if (lane == 0) { ws4[wid] = sm; ws4[4 + wid] = sq; }
    __syncthreads();
    sm = ws4[0] + ws4[1] + ws4[2] + ws4[3];
    sq = ws4[4] + ws4[5] + ws4[6] + ws4[7];
    const float mu = sm * (1.f / D_);
    const float rs = rsqrtf(sq * (1.f / D_) - mu * mu + 1e-6f);
    bf16_t* row = xn + (size_t)t * 1536;
#pragma unroll
    for (int k2 = 0; k2 < 3; ++k2) {
        const int c = tid + k2 * 256;
        const float v = (k2 == 0 ? v0 : k2 == 1 ? v1 : v2);
        const float y = (v - mu) * rs * w[c] + b[c];
        bf16_t h = __float2bfloat16(y);
        row[c] = h;
        row[768 + c] = __float2bfloat16(y - __bfloat162float(h));
    }
}

// ---------------- conv(K=4)+SiLU from fp32 xl; writes compact xc-hi plane; fp32 gates fused ----------------
__global__ __launch_bounds__(192) void conv_gate_kernel(const float* __restrict__ xl,
                                                        const float* __restrict__ cw,
                                                        const float* __restrict__ fw,
                                                        const float* __restrict__ fb,
                                                        bf16_t* __restrict__ xch,
                                                        float* __restrict__ gates) {
    const int t = blockIdx.x, c = threadIdx.x;   // c: 8-float chunk, 192*8 = 1536
    const float* row = xl + (size_t)t * P_;
    const float4* r4 = (const float4*)row;
    float4 a = r4[2 * c], b4 = r4[2 * c + 1];
    float pm3 = 0.f, pm2 = 0.f, pm1 = 0.f;
    if (c > 0) { pm3 = row[c * 8 - 3]; pm2 = row[c * 8 - 2]; pm1 = row[c * 8 - 1]; }
    const float w0 = cw[0], w1 = cw[1], w2 = cw[2], w3 = cw[3];
    float xv[11] = {pm3, pm2, pm1, a.x, a.y, a.z, a.w, b4.x, b4.y, b4.z, b4.w};
    float xc[8];
    u16x8 h8;
#pragma unroll
    for (int j = 0; j < 8; ++j) {
        float s = w0 * xv[j] + w1 * xv[j + 1] + w2 * xv[j + 2] + w3 * xv[j + 3];
        s = s * (1.f / (1.f + __expf(-s)));   // SiLU
        xc[j] = s;
        h8[j] = f2b(s);
    }
    *(u16x8*)(xch + (size_t)t * P_ + c * 8) = h8;

    // fused exact-fp32 gate dots: z_j = sum_p xc_p * fw[j*1536+p], j = 0..15
    float pj[16];
#pragma unroll
    for (int j = 0; j < 16; ++j) {
        const float* wr = fw + (size_t)j * P_ + c * 8;
        float p = 0.f;
#pragma unroll
        for (int u = 0; u < 8; ++u) p += xc[u] * wr[u];
        pj[j] = p;
    }
#pragma unroll
    for (int j = 0; j < 16; ++j)
#pragma unroll
        for (int off = 32; off > 0; off >>= 1) pj[j] += __shfl_xor(pj[j], off);
    __shared__ float red[3][16];
    const int wv = c >> 6, ln = c & 63;
    if (ln == 0) {
#pragma unroll
        for (int j = 0; j < 16; ++j) red[wv][j] = pj[j];
    }
    __syncthreads();
    if (c < 16) {
        const float z = red[0][c] + red[1][c] + red[2][c] + fb[c];
        gates[(size_t)t * 16 + c] = 15.f * tanhf(z * (1.f / 15.f));
    }
}

// ============== 256x256 8-phase pipelined bf16 MFMA GEMM, C = A[M,K] * W[N,K]^T ==============
// Virtual K-tile stream folds the precision passes: pass 0: Ah*Wh; 1: Ah*Wl; 2: (A+aloff)*Wh.
// 8 waves (2M x 4N), per-wave 128x64 output, BK=64, LDS = 8 half-tile slots x 16KB (128KB, dbuf).
// Swizzle: linear LDS dest (global_load_lds), global source chunk ^= row&7, ds_read chunk ^= row&7.
// Schedule per tile vt (phases q0..q3): stage stream h = 4*vt + 6 + q
//   q0: read a03(8) + b01(4) | stage (vt+1)Bh0 | bar | MFMA rf0-3 x cf0-1 | bar
//   q1: read a47(8)          | stage (vt+1)Bh1 | bar | MFMA rf4-7 x cf0-1 | bar
//   q2: read b23(4)          | stage (vt+2)Ah0 | bar | MFMA rf4-7 x cf2-3 | bar
//   q3: (regs only)          | stage (vt+2)Ah1 | bar | MFMA rf0-3 x cf2-3 | vmcnt(4) bar
// Safety: A-half slot reads complete by q1 (lgkm before q1 MFMA, barrier), re-staged q2/q3;
// B-half slots read q0/q2, re-staged next tile q0/q1. vmcnt(4) = 2 half-tiles outstanding.
template <int NPASS, int MODE, int KTP>
__global__ __launch_bounds__(512, 2) void gemm256(
    const char* __restrict__ Ab, int astride, int aloff,
    const bf16_t* __restrict__ Wh, const bf16_t* __restrict__ Wl,
    bf16_t* __restrict__ out0, float* __restrict__ outf, int ldout,
    bf16_t* __restrict__ oq, bf16_t* __restrict__ ok, bf16_t* __restrict__ ov,
    const float* __restrict__ bias, const float* __restrict__ resid) {
    __shared__ char smem[131072];
    const int tid = threadIdx.x;
    const int nt = blockIdx.x, mt = blockIdx.y;
    const int wid = tid >> 6, lane = tid & 63;
    const int wm = wid >> 2, wn = wid & 3;
    const int l15 = lane & 15, l4 = lane >> 4;
    const int sw = l15 & 7;
    constexpr int VT = NPASS * KTP;
    const size_t wstride = (size_t)KTP * 128;   // W row bytes

    auto stage = [&](int h) {
        const int t = h >> 2;
        if (t >= VT) return;
        const int m = h & 3;
        const int pass = t / KTP;
        const int k0b = (t - pass * KTP) << 7;
        char* ldsdst = smem + (size_t)(h & 7) * 16384;
        const char* src;
        size_t stride;
        if (m < 2) {
            src = Ab + (pass == 2 ? aloff : 0) + (size_t)(mt * 256 + m * 128) * astride + k0b;
            stride = (size_t)astride;
        } else {
            const bf16_t* wp = (pass == 1) ? Wl : Wh;
            src = (const char*)wp + (size_t)(nt * 256 + (m - 2) * 128) * wstride + k0b;
            stride = wstride;
        }
        const int r0 = tid >> 3, cd = tid & 7;
#pragma unroll
        for (int l = 0; l < 2; ++l) {
            const int row = l * 64 + r0;
            gload16(src + (size_t)row * stride + (size_t)((cd ^ (row & 7)) << 4),
                    ldsdst + l * 8192 + tid * 16);
        }
    };

    f32x4 acc[8][4];
#pragma unroll
    for (int i = 0; i < 8; ++i)
#pragma unroll
        for (int j = 0; j < 4; ++j) acc[i][j] = f32x4{0.f, 0.f, 0.f, 0.f};

    // prologue: tile0 all 4 halves + tile1 A-halves
#pragma unroll
    for (int h = 0; h < 6; ++h) stage(h);
    asm volatile("s_waitcnt vmcnt(4)" ::: "memory");
    __builtin_amdgcn_s_barrier();

    s16x8 a03[4][2], a47[4][2], bb[2][2];

    for (int vt = 0; vt < VT; ++vt) {
        const char* ldsA = smem + (vt & 1) * 65536 + wm * 16384;
        const char* ldsB = smem + (vt & 1) * 65536 + 32768 + (wn >> 1) * 16384;
        const int brb = (wn & 1) * 64;
        const int hb = vt * 4 + 6;

        // ---- phase 0
#pragma unroll
        for (int i = 0; i < 4; ++i) {
            const int row = i * 16 + l15;
#pragma unroll
            for (int kk = 0; kk < 2; ++kk)
                a03[i][kk] = *(const s16x8*)(ldsA + row * 128 + ((((kk << 2) | l4) ^ sw) << 4));
        }
#pragma unroll
        for (int j = 0; j < 2; ++j) {
            const int row = brb + j * 16 + l15;
#pragma unroll
            for (int kk = 0; kk < 2; ++kk)
                bb[j][kk] = *(const s16x8*)(ldsB + row * 128 + ((((kk << 2) | l4) ^ sw) << 4));
        }
        stage(hb + 0);
        __builtin_amdgcn_s_barrier();
        __builtin_amdgcn_s_setprio(1);
#pragma unroll
        for (int i = 0; i < 4; ++i)
#pragma unroll
            for (int j = 0; j < 2; ++j)
#pragma unroll
                for (int kk = 0; kk < 2; ++kk)
                    acc[i][j] = __builtin_amdgcn_mfma_f32_16x16x32_bf16(a03[i][kk], bb[j][kk], acc[i][j], 0, 0, 0);
        __builtin_amdgcn_s_setprio(0);
        __builtin_amdgcn_s_barrier();

        // ---- phase 1
#pragma unroll
        for (int i = 0; i < 4; ++i) {
            const int row = (4 + i) * 16 + l15;
#pragma unroll
            for (int kk = 0; kk < 2; ++kk)
                a47[i][kk] = *(const s16x8*)(ldsA + row * 128 + ((((kk << 2) | l4) ^ sw) << 4));
        }
        stage(hb + 1);
        __builtin_amdgcn_s_barrier();
        __builtin_amdgcn_s_setprio(1);
#pragma unroll
        for (int i = 0; i < 4; ++i)
#pragma unroll
            for (int j = 0; j < 2; ++j)
#pragma unroll
                for (int kk = 0; kk < 2; ++kk)
                    acc[4 + i][j] = __builtin_amdgcn_mfma_f32_16x16x32_bf16(a47[i][kk], bb[j][kk], acc[4 + i][j], 0, 0, 0);
        __builtin_amdgcn_s_setprio(0);
        __builtin_amdgcn_s_barrier();

        // ---- phase 2
#pragma unroll
        for (int j = 0; j < 2; ++j) {
            const int row = brb + (2 + j) * 16 + l15;
#pragma unroll
            for (int kk = 0; kk < 2; ++kk)
                bb[j][kk] = *(const s16x8*)(ldsB + row * 128 + ((((kk << 2) | l4) ^ sw) << 4));
        }
        stage(hb + 2);
        __builtin_amdgcn_s_barrier();
        __builtin_amdgcn_s_setprio(1);
#pragma unroll
        for (int i = 0; i < 4; ++i)
#pragma unroll
            for (int j = 0; j < 2; ++j)
#pragma unroll
                for (int kk = 0; kk < 2; ++kk)
                    acc[4 + i][2 + j] = __builtin_amdgcn_mfma_f32_16x16x32_bf16(a47[i][kk], bb[j][kk], acc[4 + i][2 + j], 0, 0, 0);
        __builtin_amdgcn_s_setprio(0);
        __builtin_amdgcn_s_barrier();

        // ---- phase 3 (register-only reads)
        stage(hb + 3);
        __builtin_amdgcn_s_barrier();
        __builtin_amdgcn_s_setprio(1);
#pragma unroll
        for (int i = 0; i < 4; ++i)
#pragma unroll
            for (int j = 0; j < 2; ++j)
#pragma unroll
                for (int kk = 0; kk < 2; ++kk)
                    acc[i][2 + j] = __builtin_amdgcn_mfma_f32_16x16x32_bf16(a03[i][kk], bb[j][kk], acc[i][2 + j], 0, 0, 0);
        __builtin_amdgcn_s_setprio(0);
        asm volatile("s_waitcnt vmcnt(4)" ::: "memory");
        __builtin_amdgcn_s_barrier();
    }

    // ---- epilogue ----
    const int grow0 = mt * 256 + wm * 128;
    const int gcol0 = nt * 256 + wn * 64;
#pragma unroll
    for (int i = 0; i < 8; ++i) {
#pragma unroll
        for (int j = 0; j < 4; ++j) {
            const int gcol = gcol0 + j * 16 + l15;
#pragma unroll
            for (int r = 0; r < 4; ++r) {
                const int grow = grow0 + i * 16 + l4 * 4 + r;
                float v = acc[i][j][r];
                if constexpr (MODE == 0) {
                    out0[(size_t)grow * ldout + gcol] = __float2bfloat16(v);
                } else if constexpr (MODE == 1) {
                    outf[(size_t)grow * ldout + gcol] = v;
                } else if constexpr (MODE == 2) {
                    v += bias[gcol];
                    const int seg = gcol / 768;          // uniform per block (768 % 256 == 0)
                    const int col = gcol - seg * 768;
                    const size_t oo = (size_t)grow * 768 + col;
                    if (seg == 0)      out0[oo] = __float2bfloat16(1.f / (1.f + __expf(-v)));
                    else if (seg == 1) oq[oo] = __float2bfloat16(v);
                    else if (seg == 2) ok[oo] = __float2bfloat16(v * 0.10206207261596577f); // 1/sqrt(96)
                    else               ov[oo] = __float2bfloat16(v);
                } else {
                    const size_t oo = (size_t)grow * ldout + gcol;
                    outf[oo] = v + resid[oo];
                }
            }
        }
    }
}

// ================= chunkwise-parallel mLSTM recurrence =================
// ---- 1. gate scan: 1 block per batch b, 64 threads = 8 heads x 8 chunks ----
__global__ __launch_bounds__(64) void mscan_kernel(const float* __restrict__ gates,
                                                   float* __restrict__ wAo, float* __restrict__ go,
                                                   float* __restrict__ mprev, float* __restrict__ alpha) {
    const int b = blockIdx.x;
    const int lane = threadIdx.x;
    const int hd = lane >> 3, c = lane & 7;
    const size_t gbase = ((size_t)b * S_ + c * LCH) * 16;
    float F = 0.f, I = -1e30f;
    for (int t = 0; t < LCH; ++t) {
        const float fi = gates[gbase + t * 16 + hd];
        const float ff = gates[gbase + t * 16 + 8 + hd];
        I = fmaxf(I + ff, fi);
        F += ff;
    }
    float Fs = F, Is = I;
#pragma unroll
    for (int off = 1; off < 8; off <<= 1) {
        const float Fo = __shfl_up(Fs, off);
        const float Io = __shfl_up(Is, off);
        if (c >= off) { Is = fmaxf(Io + Fs, Is); Fs = Fo + Fs; }
    }
    const float Fe = __shfl_up(Fs, 1);
    const float Ie = __shfl_up(Is, 1);
    const float mp = (c == 0) ? 0.f : fmaxf(Fe, Ie);
    float m = mp; F = 0.f;
    const size_t wbase = ((size_t)(b * NH_ + hd)) * S_ + c * LCH;
    for (int t = 0; t < LCH; ++t) {
        const float fi = gates[gbase + t * 16 + hd];
        const float ff = gates[gbase + t * 16 + 8 + hd];
        F += ff;
        m = fmaxf(ff + m, fi);
        wAo[wbase + t] = fi - F;
        go[wbase + t] = F - m;
    }
    const int idx = (b * NH_ + hd) * NCH + c;
    mprev[idx] = mp;
    alpha[idx] = __expf(fminf(mp + F - m, 0.f));
}

// ---- 2. chunk summaries ----
__global__ __launch_bounds__(512) void chunkA_kernel(
    const bf16_t* __restrict__ kb, const bf16_t* __restrict__ vb,
    const float* __restrict__ wAo, const float* __restrict__ go,
    float* __restrict__ Bst) {
    const int c = blockIdx.x, bh = blockIdx.y;
    const int b = bh >> 3, hd = bh & 7;
    __shared__ bf16_t kT[96 * 136];
    __shared__ bf16_t vTh[96 * 136];
    __shared__ bf16_t vTl[96 * 136];
    __shared__ float coeffL[128];
    const int tid = threadIdx.x, lane = tid & 63, wid = tid >> 6;
    const int l15 = lane & 15, l4 = lane >> 4;
    const int s0 = c * LCH;
    const size_t seqb = (size_t)bh * S_;
    const float gend = go[seqb + s0 + LCH - 1];
    f32x4 acc[6];
#pragma unroll
    for (int nf = 0; nf < 6; ++nf) acc[nf] = f32x4{0.f, 0.f, 0.f, 0.f};
    float nacc = 0.f;
    const int ne = tid - 384;

    for (int sb = 0; sb < 2; ++sb) {
        __syncthreads();
        if (tid < 128) coeffL[tid] = __expf(fminf(wAo[seqb + s0 + sb * 128 + tid] + gend, 0.f));
        __syncthreads();
        {
            const int st = tid >> 2, e0 = (tid & 3) * 24;
            const size_t rowb = (size_t)(b * S_ + s0 + sb * 128 + st) * HID_ + hd * DH_ + e0;
            const float cf = coeffL[st];
#pragma unroll
            for (int jj = 0; jj < 3; ++jj) {
                const u16x8 kv = *(const u16x8*)(kb + rowb + jj * 8);
                const u16x8 vv = *(const u16x8*)(vb + rowb + jj * 8);
#pragma unroll
                for (int u = 0; u < 8; ++u) {
                    const int e = e0 + jj * 8 + u;
                    kT[e * 136 + st] = u2b(kv[u]);
                    const float vf = b2f(vv[u]) * cf;
                    const bf16_t hh = __float2bfloat16(vf);
                    vTh[e * 136 + st] = hh;
                    vTl[e * 136 + st] = __float2bfloat16(vf - __bfloat162float(hh));
                }
            }
        }
        __syncthreads();
        if (wid < 6) {
#pragma unroll
            for (int pass = 0; pass < 2; ++pass) {
                const bf16_t* Ap = pass ? vTl : vTh;
#pragma unroll
                for (int ks = 0; ks < 4; ++ks) {
                    const s16x8 af = *(const s16x8*)((const char*)Ap + (wid * 16 + l15) * 272 + ks * 64 + l4 * 16);
#pragma unroll
                    for (int nf = 0; nf < 6; ++nf) {
                        const s16x8 bf = *(const s16x8*)((const char*)kT + (nf * 16 + l15) * 272 + ks * 64 + l4 * 16);
                        acc[nf] = __builtin_amdgcn_mfma_f32_16x16x32_bf16(af, bf, acc[nf], 0, 0, 0);
                    }
                }
            }
        } else if (ne < 96) {
            for (int sg = 0; sg < 128; ++sg)
                nacc += coeffL[sg] * __bfloat162float(kT[ne * 136 + sg]);
        }
    }
    float* outp = Bst + ((size_t)bh * NCH + c) * 9312;
    if (wid < 6) {
#pragma unroll
        for (int nf = 0; nf < 6; ++nf)
#pragma unroll
            for (int r = 0; r < 4; ++r)
                outp[(size_t)(wid * 16 + l4 * 4 + r) * 96 + nf * 16 + l15] = acc[nf][r];
    } else if (ne < 96) {
        outp[9216 + ne] = nacc;
    }
}

// ---- 3. inter-chunk scan, in-place ----
__global__ __launch_bounds__(96) void chunkB_kernel(float* __restrict__ Bst,
                                                    const float* __restrict__ alpha) {
    const int idx = blockIdx.x * 96 + threadIdx.x;
    const int bh = blockIdx.y;
    float val = (idx < 9216) ? 0.f : 1.f;
    for (int c = 0; c < NCH; ++c) {
        float* p = Bst + ((size_t)bh * NCH + c) * 9312 + idx;
        const float t = *p;
        *p = val;
        val = alpha[bh * NCH + c] * val + t;
    }
}

// ---- 4. outputs ----
__global__ __launch_bounds__(256) void chunkC_kernel(
    const bf16_t* __restrict__ qb, const bf16_t* __restrict__ kb,
    const bf16_t* __restrict__ vb, const bf16_t* __restrict__ ob,
    const float* __restrict__ wAo, const float* __restrict__ go,
    const float* __restrict__ mprev, const float* __restrict__ Cst,
    float* __restrict__ hb) {
    const int c = blockIdx.x >> 2, qblk = blockIdx.x & 3;
    const int bh = blockIdx.y, b = bh >> 3, hd = bh & 7;
    __shared__ bf16_t Qs[64 * 104];
    __shared__ bf16_t Ks[64 * 104];
    __shared__ bf16_t vTs[112 * 72];
    __shared__ bf16_t Phs[64 * 72];
    __shared__ bf16_t Pls[64 * 72];
    __shared__ bf16_t CsH[112 * 104];
    __shared__ bf16_t CsL[112 * 104];
    __shared__ float wAL[256];
    __shared__ float gL[64];
    __shared__ float scL[64];
    const int tid = threadIdx.x, lane = tid & 63, wid = tid >> 6;
    const int l15 = lane & 15, l4 = lane >> 4;
    const int s0 = c * LCH;
    const size_t seqb = (size_t)bh * S_;
    const int tq0 = b * S_ + s0 + qblk * 64;

    wAL[tid] = wAo[seqb + s0 + tid];
    if (tid < 64) {
        const float gg = go[seqb + s0 + qblk * 64 + tid];
        gL[tid] = gg;
        scL[tid] = __expf(fminf(mprev[bh * NCH + c] + gg, 0.f));
    }
    {
        const int tt = tid >> 2, e0 = (tid & 3) * 24;
        const bf16_t* qrow = qb + (size_t)(tq0 + tt) * HID_ + hd * DH_ + e0;
#pragma unroll
        for (int jj = 0; jj < 3; ++jj)
            *(u16x8*)&Qs[tt * 104 + e0 + jj * 8] = *(const u16x8*)(qrow + jj * 8);
    }
    {
        const float* Csp = Cst + ((size_t)bh * NCH + c) * 9312;
        for (int i = tid; i < 9312; i += 256) {
            int dd, ee;
            if (i < 9216) { dd = i / 96; ee = i - dd * 96; }
            else          { dd = 96;     ee = i - 9216; }
            const float xv = Csp[i];
            const bf16_t hh = __float2bfloat16(xv);
            CsH[dd * 104 + ee] = hh;
            CsL[dd * 104 + ee] = __float2bfloat16(xv - __bfloat162float(hh));
        }
        const bf16_t z16 = __float2bfloat16(0.f);
        for (int i = tid; i < 15 * 104; i += 256) { CsH[97 * 104 + i] = z16; CsL[97 * 104 + i] = z16; }
        if (tid < 64) vTs[96 * 72 + tid] = __float2bfloat16(1.f);
        for (int i = tid; i < 15 * 72; i += 256) vTs[97 * 72 + i] = z16;
    }
    __syncthreads();

    f32x4 acc[7];
#pragma unroll
    for (int nf = 0; nf < 7; ++nf) acc[nf] = f32x4{0.f, 0.f, 0.f, 0.f};
#pragma unroll
    for (int pass = 0; pass < 2; ++pass) {
        const bf16_t* Cp = pass ? CsL : CsH;
#pragma unroll
        for (int ks = 0; ks < 3; ++ks) {
            const s16x8 af = *(const s16x8*)((const char*)Qs + (wid * 16 + l15) * 208 + ks * 64 + l4 * 16);
#pragma unroll
            for (int nf = 0; nf < 7; ++nf) {
                const s16x8 bf = *(const s16x8*)((const char*)Cp + (nf * 16 + l15) * 208 + ks * 64 + l4 * 16);
                acc[nf] = __builtin_amdgcn_mfma_f32_16x16x32_bf16(af, bf, acc[nf], 0, 0, 0);
            }
        }
    }
    {
        float scr[4];
#pragma unroll
        for (int r = 0; r < 4; ++r) scr[r] = scL[wid * 16 + l4 * 4 + r];
#pragma unroll
        for (int nf = 0; nf < 7; ++nf)
#pragma unroll
            for (int r = 0; r < 4; ++r) acc[nf][r] *= scr[r];
    }

    for (int sb = 0; sb <= qblk; ++sb) {
        __syncthreads();
        {
            const int tt = tid >> 2, e0 = (tid & 3) * 24;
            const size_t rowb = (size_t)(b * S_ + s0 + sb * 64 + tt) * HID_ + hd * DH_ + e0;
#pragma unroll
            for (int jj = 0; jj < 3; ++jj) {
                *(u16x8*)&Ks[tt * 104 + e0 + jj * 8] = *(const u16x8*)(kb + rowb + jj * 8);
                const u16x8 vv = *(const u16x8*)(vb + rowb + jj * 8);
#pragma unroll
                for (int u = 0; u < 8; ++u)
                    vTs[(e0 + jj * 8 + u) * 72 + tt] = u2b(vv[u]);
            }
        }
        __syncthreads();
        f32x4 pacc[4];
#pragma unroll
        for (int nf = 0; nf < 4; ++nf) pacc[nf] = f32x4{0.f, 0.f, 0.f, 0.f};
#pragma unroll
        for (int ks = 0; ks < 3; ++ks) {
            const s16x8 af = *(const s16x8*)((const char*)Qs + (wid * 16 + l15) * 208 + ks * 64 + l4 * 16);
#pragma unroll
            for (int nf = 0; nf < 4; ++nf) {
                const s16x8 bf = *(const s16x8*)((const char*)Ks + (nf * 16 + l15) * 208 + ks * 64 + l4 * 16);
                pacc[nf] = __builtin_amdgcn_mfma_f32_16x16x32_bf16(af, bf, pacc[nf], 0, 0, 0);
            }
        }
#pragma unroll
        for (int nf = 0; nf < 4; ++nf) {
#pragma unroll
            for (int r = 0; r < 4; ++r) {
                const int tr = wid * 16 + l4 * 4 + r;
                const int sg = nf * 16 + l15;
                float p = 0.f;
                if (sb < qblk || sg <= tr)
                    p = pacc[nf][r] * __expf(fminf(wAL[sb * 64 + sg] + gL[tr], 0.f));
                const bf16_t hh = __float2bfloat16(p);
                Phs[tr * 72 + sg] = hh;
                Pls[tr * 72 + sg] = __float2bfloat16(p - __bfloat162float(hh));
            }
        }
        __syncthreads();
#pragma unroll
        for (int pass = 0; pass < 2; ++pass) {
            const bf16_t* Pp = pass ? Pls : Phs;
#pragma unroll
            for (int ks = 0; ks < 2; ++ks) {
                const s16x8 af = *(const s16x8*)((const char*)Pp + (wid * 16 + l15) * 144 + ks * 64 + l4 * 16);
#pragma unroll
                for (int nf = 0; nf < 7; ++nf) {
                    const s16x8 bf = *(const s16x8*)((const char*)vTs + (nf * 16 + l15) * 144 + ks * 64 + l4 * 16);
                    acc[nf] = __builtin_amdgcn_mfma_f32_16x16x32_bf16(af, bf, acc[nf], 0, 0, 0);
                }
            }
        }
    }

#pragma unroll
    for (int r = 0; r < 4; ++r) {
        float den = __shfl(acc[6][r], lane & 48);
        den = fmaxf(den, 1.0f);
        const int tr = wid * 16 + l4 * 4 + r;
        const size_t rowb = (size_t)(tq0 + tr) * HID_ + hd * DH_;
#pragma unroll
        for (int nf = 0; nf < 6; ++nf) {
            const int dc = nf * 16 + l15;
            const float o = __bfloat162float(ob[rowb + dc]);
            hb[rowb + dc] = o * acc[nf][r] / den;
        }
    }
}

// ---------------- (LN(h)+skip)*silu(r) -> pre hi/lo pair rows ----------------
__global__ __launch_bounds__(256) void epi1_kernel(const float* __restrict__ h,
                                                   const bf16_t* __restrict__ xskip,
                                                   const bf16_t* __restrict__ r,
                                                   const float* __restrict__ hw,
                                                   const float* __restrict__ hbi,
                                                   bf16_t* __restrict__ pre) {
    const int t = blockIdx.x, tid = threadIdx.x;
    const size_t rb = (size_t)t * HID_;
    float v0 = h[rb + tid], v1 = h[rb + tid + 256], v2 = h[rb + tid + 512];
    float sm = v0 + v1 + v2;
    float sq = v0 * v0 + v1 * v1 + v2 * v2;
#pragma unroll
    for (int off = 32; off > 0; off >>= 1) { sm += __shfl_xor(sm, off); sq += __shfl_xor(sq, off); }
    __shared__ float ws4[8];
    const int wid = tid >> 6, lane = tid & 63;
    if (lane == 0) { ws4[wid] = sm; ws4[4 + wid] = sq; }
    __syncthreads();
    sm = ws4[0] + ws4[1] + ws4[2] + ws4[3];
    sq = ws4[4] + ws4[5] + ws4[6] + ws4[7];
    const float mu = sm * (1.f / HID_);
    const float rs = rsqrtf(sq * (1.f / HID_) - mu * mu + 1e-6f);
    bf16_t* row = pre + (size_t)t * 1536;
#pragma unroll
    for (int k2 = 0; k2 < 3; ++k2) {
        const int c = tid + k2 * 256;
        const float v = (k2 == 0 ? v0 : k2 == 1 ? v1 : v2);
        float o = (v - mu) * rs * hw[c] + hbi[c] + __bfloat162float(xskip[rb + c]);
        const float rv = __bfloat162float(r[rb + c]);
        o *= rv * (1.f / (1.f + __expf(-rv)));
        bf16_t hh = __float2bfloat16(o);
        row[c] = hh;
        row[768 + c] = __float2bfloat16(o - __bfloat162float(hh));
    }
}

extern "C" void kernel_launch(void* const* d_in, const int* in_sizes, int n_in,
                              void* d_out, int out_size, void* d_ws, size_t ws_size,
                              hipStream_t stream) {
    const float* x      = (const float*)d_in[0];
    const float* ln_w   = (const float*)d_in[1];
    const float* ln_b   = (const float*)d_in[2];
    const float* up_l_w = (const float*)d_in[3];
    const float* up_r_w = (const float*)d_in[4];
    const float* conv_w = (const float*)d_in[5];
    const float* skip_w = (const float*)d_in[6];
    const float* fused_w= (const float*)d_in[7];
    const float* fused_b= (const float*)d_in[8];
    const float* hid_w  = (const float*)d_in[9];
    const float* hid_b  = (const float*)d_in[10];
    const float* down_w = (const float*)d_in[11];
    float* out = (float*)d_out;
    (void)n_in; (void)out_size; (void)ws_size;

    const size_t T = (size_t)in_sizes[0] / D_;   // 16384
    const int B = (int)(T / S_);                 // 8

    // ---- workspace layout: 231.9 MB total (proven-safe, same as round 3/4) ----
    char* ws = (char*)d_ws;
    size_t off = 0;
    auto take = [&](size_t bytes) -> char* {
        char* p = ws + off; off = (off + bytes + 255) & ~(size_t)255; return p;
    };
    bf16_t* wul_h = (bf16_t*)take((size_t)P_ * D_ * 2);      // @0 (pool, dead after fused GEMM)
    bf16_t* wul_l = (bf16_t*)take((size_t)P_ * D_ * 2);
    bf16_t* wur   = (bf16_t*)take((size_t)HID_ * D_ * 2);
    bf16_t* wsk   = (bf16_t*)take((size_t)HID_ * P_ * 2);
    bf16_t* wfu_h = (bf16_t*)take((size_t)3072 * P_ * 2);
    bf16_t* wfu_l = (bf16_t*)take((size_t)3072 * P_ * 2);
    bf16_t* wdn_h = (bf16_t*)take((size_t)D_ * HID_ * 2);
    bf16_t* wdn_l = (bf16_t*)take((size_t)D_ * HID_ * 2);
    char*   xnreg = take(T * 1536 * 2);   // ln hi/lo -> compact xc-hi plane -> h fp32
    char*   big   = take(T * 1536 * 4);   // xl fp32 -> [o|q|k|v] bf16 -> pre hi/lo
    bf16_t* rbuf  = (bf16_t*)take(T * HID_ * 2);
    bf16_t* skipb = (bf16_t*)take(T * HID_ * 2);
    float*  gates = (float*)take(T * 16 * 4);

    bf16_t* xn   = (bf16_t*)xnreg;
    bf16_t* xch  = (bf16_t*)xnreg;
    float*  h    = (float*)xnreg;
    float*  xl   = (float*)big;
    bf16_t* obuf = (bf16_t*)big;
    bf16_t* qbuf = (bf16_t*)(big + T * HID_ * 2);
    bf16_t* kbuf = (bf16_t*)(big + T * HID_ * 4);
    bf16_t* vbuf = (bf16_t*)(big + T * HID_ * 6);
    bf16_t* pre  = (bf16_t*)big;

    // recurrence scratch aliased over the dead weight pool [0, 27.1MB)
    float* Bst    = (float*)ws;                         // 19,070,976 B
    float* wAarr  = (float*)(ws + 19071232);
    float* garr   = (float*)(ws + 19595520);
    float* mprevA = (float*)(ws + 20119808);
    float* alphaA = (float*)(ws + 20121856);

    const int MT = (int)(T / 256);   // 64

    // 1. weight conversions
    cvt2_kernel<<<512, 256, 0, stream>>>(up_l_w, wul_h, wul_l, P_ * D_);
    cvt_kernel <<<512, 256, 0, stream>>>(up_r_w, wur, HID_ * D_);
    cvt_kernel <<<512, 256, 0, stream>>>(skip_w, wsk, HID_ * P_);
    cvt2_kernel<<<2048, 256, 0, stream>>>(fused_w + (size_t)16 * P_, wfu_h, wfu_l, 3072 * P_);
    cvt2_kernel<<<512, 256, 0, stream>>>(down_w, wdn_h, wdn_l, D_ * HID_);
    // 2. LayerNorm -> xn hi/lo
    ln_x_kernel<<<(int)T, 256, 0, stream>>>(x, ln_w, ln_b, xn);
    // 3. xl = xn @ up_l^T (3-pass split, fp32 out)    K=768 -> KTP=12
    gemm256<3, 1, 12><<<dim3(P_ / 256, MT), 512, 0, stream>>>(
        (const char*)xn, 3072, 1536, wul_h, wul_l,
        nullptr, xl, P_, nullptr, nullptr, nullptr, nullptr, nullptr);
    // 4. r = xn_hi @ up_r^T (1-pass)
    gemm256<1, 0, 12><<<dim3(HID_ / 256, MT), 512, 0, stream>>>(
        (const char*)xn, 3072, 0, wur, nullptr,
        rbuf, nullptr, HID_, nullptr, nullptr, nullptr, nullptr, nullptr);
    // 5. conv+silu -> compact xc-hi plane; exact fp32 gates fused in
    conv_gate_kernel<<<(int)T, 192, 0, stream>>>(xl, conv_w, fused_w, fused_b, xch, gates);
    // 6. x_skip = xc_hi @ skip^T (1-pass)             K=1536 -> KTP=24
    gemm256<1, 0, 24><<<dim3(HID_ / 256, MT), 512, 0, stream>>>(
        (const char*)xch, 3072, 0, wsk, nullptr,
        skipb, nullptr, HID_, nullptr, nullptr, nullptr, nullptr, nullptr);
    // 7. o,q,k,v = xc_hi @ fused[16:]^T (2-pass; +bias, activations)
    gemm256<2, 2, 24><<<dim3(3072 / 256, MT), 512, 0, stream>>>(
        (const char*)xch, 3072, 0, wfu_h, wfu_l,
        obuf, nullptr, 0, qbuf, kbuf, vbuf, fused_b + 16, nullptr);
    // 8. chunkwise-parallel recurrence -> h fp32
    mscan_kernel<<<B, 64, 0, stream>>>(gates, wAarr, garr, mprevA, alphaA);
    chunkA_kernel<<<dim3(NCH, B * NH_), 512, 0, stream>>>(kbuf, vbuf, wAarr, garr, Bst);
    chunkB_kernel<<<dim3(97, B * NH_), 96, 0, stream>>>(Bst, alphaA);
    chunkC_kernel<<<dim3(NCH * 4, B * NH_), 256, 0, stream>>>(qbuf, kbuf, vbuf, obuf,
                                                              wAarr, garr, mprevA, Bst, h);
    // 9. (LN(h)+skip)*silu(r) -> pre hi/lo
    epi1_kernel<<<(int)T, 256, 0, stream>>>(h, skipb, rbuf, hid_w, hid_b, pre);
    // 10. out = pre @ down^T + x (3-pass split)       K=768 -> KTP=12
    gemm256<3, 3, 12><<<dim3(HID_ / 256, MT), 512, 0, stream>>>(
        (const char*)pre, 3072, 1536, wdn_h, wdn_l,
        nullptr, out, HID_, nullptr, nullptr, nullptr, nullptr, x);
}

// Round 6
// 822.555 us; speedup vs baseline: 4.5721x; 1.1404x over previous
//
#include <hip/hip_runtime.h>
#include <hip/hip_bf16.h>

#define D_    768
#define P_    1536
#define HID_  768
#define NH_   8
#define DH_   96
#define S_    2048
#define LCH   256     // recurrence chunk length
#define NCH   8       // chunks per sequence

typedef __hip_bfloat16 bf16_t;
typedef __attribute__((ext_vector_type(8))) short s16x8;
typedef __attribute__((ext_vector_type(8))) unsigned short u16x8;
typedef __attribute__((ext_vector_type(4))) float f32x4;

__device__ __forceinline__ float b2f(unsigned short u) {
    union { unsigned int i; float f; } x; x.i = ((unsigned int)u) << 16; return x.f;
}
__device__ __forceinline__ unsigned short f2b(float f) {
    bf16_t h = __float2bfloat16(f);
    unsigned short u; __builtin_memcpy(&u, &h, 2); return u;
}
__device__ __forceinline__ bf16_t u2b(unsigned short u) {
    bf16_t t; __builtin_memcpy(&t, &u, 2); return t;
}

// async global->LDS, 16B per lane (LDS dest = wave-uniform base + lane*16, linear layout)
__device__ __forceinline__ void gload16(const void* g, const void* l) {
    __builtin_amdgcn_global_load_lds(
        (const __attribute__((address_space(1))) unsigned int*)(unsigned long long)(g),
        (__attribute__((address_space(3))) unsigned int*)(unsigned int)(unsigned long long)(l),
        16, 0, 0);
}

// ---------------- fp32 -> bf16 (single) ----------------
__global__ void cvt_kernel(const float* __restrict__ src, bf16_t* __restrict__ dst, int n) {
    int i = blockIdx.x * blockDim.x + threadIdx.x;
    int stride = gridDim.x * blockDim.x;
    for (; i < n; i += stride) dst[i] = __float2bfloat16(src[i]);
}

// ---------------- fp32 -> bf16 hi/lo split ----------------
__global__ void cvt2_kernel(const float* __restrict__ src, bf16_t* __restrict__ hi,
                            bf16_t* __restrict__ lo, int n) {
    int i = blockIdx.x * blockDim.x + threadIdx.x;
    int stride = gridDim.x * blockDim.x;
    for (; i < n; i += stride) {
        float x = src[i];
        bf16_t h = __float2bfloat16(x);
        hi[i] = h;
        lo[i] = __float2bfloat16(x - __bfloat162float(h));
    }
}

// ---------------- LayerNorm(x) -> bf16 hi/lo pair rows [hi 768 | lo 768] ----------------
__global__ __launch_bounds__(256) void ln_x_kernel(const float* __restrict__ x,
                                                   const float* __restrict__ w,
                                                   const float* __restrict__ b,
                                                   bf16_t* __restrict__ xn) {
    const int t = blockIdx.x, tid = threadIdx.x;
    const size_t rb = (size_t)t * D_;
    float v0 = x[rb + tid], v1 = x[rb + tid + 256], v2 = x[rb + tid + 512];
    float sm = v0 + v1 + v2;
    float sq = v0 * v0 + v1 * v1 + v2 * v2;
#pragma unroll
    for (int off = 32; off > 0; off >>= 1) { sm += __shfl_xor(sm, off); sq += __shfl_xor(sq, off); }
    __shared__ float ws4[8];
    const int wid = tid >> 6, lane = tid & 63;
    if (lane == 0) { ws4[wid] = sm; ws4[4 + wid] = sq; }
    __syncthreads();
    sm = ws4[0] + ws4[1] + ws4[2] + ws4[3];
    sq = ws4[4] + ws4[5] + ws4[6] + ws4[7];
    const float mu = sm * (1.f / D_);
    const float rs = rsqrtf(sq * (1.f / D_) - mu * mu + 1e-6f);
    bf16_t* row = xn + (size_t)t * 1536;
#pragma unroll
    for (int k2 = 0; k2 < 3; ++k2) {
        const int c = tid + k2 * 256;
        const float v = (k2 == 0 ? v0 : k2 == 1 ? v1 : v2);
        const float y = (v - mu) * rs * w[c] + b[c];
        bf16_t h = __float2bfloat16(y);
        row[c] = h;
        row[768 + c] = __float2bfloat16(y - __bfloat162float(h));
    }
}

// ---------------- conv(K=4)+SiLU from fp32 xl; writes compact xc-hi plane; fp32 gates fused ----------------
__global__ __launch_bounds__(192) void conv_gate_kernel(const float* __restrict__ xl,
                                                        const float* __restrict__ cw,
                                                        const float* __restrict__ fw,
                                                        const float* __restrict__ fb,
                                                        bf16_t* __restrict__ xch,
                                                        float* __restrict__ gates) {
    const int t = blockIdx.x, c = threadIdx.x;   // c: 8-float chunk, 192*8 = 1536
    const float* row = xl + (size_t)t * P_;
    const float4* r4 = (const float4*)row;
    float4 a = r4[2 * c], b4 = r4[2 * c + 1];
    float pm3 = 0.f, pm2 = 0.f, pm1 = 0.f;
    if (c > 0) { pm3 = row[c * 8 - 3]; pm2 = row[c * 8 - 2]; pm1 = row[c * 8 - 1]; }
    const float w0 = cw[0], w1 = cw[1], w2 = cw[2], w3 = cw[3];
    float xv[11] = {pm3, pm2, pm1, a.x, a.y, a.z, a.w, b4.x, b4.y, b4.z, b4.w};
    float xc[8];
    u16x8 h8;
#pragma unroll
    for (int j = 0; j < 8; ++j) {
        float s = w0 * xv[j] + w1 * xv[j + 1] + w2 * xv[j + 2] + w3 * xv[j + 3];
        s = s * (1.f / (1.f + __expf(-s)));   // SiLU
        xc[j] = s;
        h8[j] = f2b(s);
    }
    *(u16x8*)(xch + (size_t)t * P_ + c * 8) = h8;

    // fused exact-fp32 gate dots: z_j = sum_p xc_p * fw[j*1536+p], j = 0..15
    float pj[16];
#pragma unroll
    for (int j = 0; j < 16; ++j) {
        const float* wr = fw + (size_t)j * P_ + c * 8;
        float p = 0.f;
#pragma unroll
        for (int u = 0; u < 8; ++u) p += xc[u] * wr[u];
        pj[j] = p;
    }
#pragma unroll
    for (int j = 0; j < 16; ++j)
#pragma unroll
        for (int off = 32; off > 0; off >>= 1) pj[j] += __shfl_xor(pj[j], off);
    __shared__ float red[3][16];
    const int wv = c >> 6, ln = c & 63;
    if (ln == 0) {
#pragma unroll
        for (int j = 0; j < 16; ++j) red[wv][j] = pj[j];
    }
    __syncthreads();
    if (c < 16) {
        const float z = red[0][c] + red[1][c] + red[2][c] + fb[c];
        gates[(size_t)t * 16 + c] = 15.f * tanhf(z * (1.f / 15.f));
    }
}

// ============== 256x256 8-phase pipelined bf16 MFMA GEMM, C = A[M,K] * W[N,K]^T ==============
// Virtual K-tile stream folds precision passes: pass 0: Ah*Wh; 1: Ah*Wl; 2: (A+aloff)*Wh.
// 8 waves (2M x 4N), per-wave 128x64, BK=64, LDS = 8 half-tile slots x 16KB (128KB dbuf).
// Swizzle: linear LDS dest (global_load_lds), global source chunk ^= row&7, ds_read chunk ^= row&7.
// vmcnt(4) once per tile (never 0 in the loop). Bijective XCD swizzle (requires nwg % 8 == 0).
// MODE 0: bf16 out0. MODE 1: fp32 outf. MODE 3: fp32 outf = acc + resid.
// MODE 2 (merged skip+qkvo, N=3840): seg0 skip->out0 (no bias); seg1 sigmoid->p1;
//         seg2 q->p2; seg3 k*1/sqrt(96)->p3; seg4 v->p4 (bias = fused_b+16 at gcol-768).
template <int NPASS, int MODE, int KTP>
__global__ __launch_bounds__(512, 2) void gemm256(
    const char* __restrict__ Ab, int astride, int aloff,
    const bf16_t* __restrict__ Wh, const bf16_t* __restrict__ Wl,
    bf16_t* __restrict__ out0, float* __restrict__ outf, int ldout,
    bf16_t* __restrict__ p1, bf16_t* __restrict__ p2,
    bf16_t* __restrict__ p3, bf16_t* __restrict__ p4,
    const float* __restrict__ bias, const float* __restrict__ resid) {
    __shared__ char smem[131072];
    const int tid = threadIdx.x;
    // bijective XCD-aware chunked swizzle (nwg % 8 == 0 guaranteed by launch)
    const int gx = gridDim.x;
    int flat = blockIdx.y * gx + blockIdx.x;
    const int cpx = (gx * gridDim.y) >> 3;
    flat = (flat & 7) * cpx + (flat >> 3);
    const int nt = flat % gx, mt = flat / gx;
    const int wid = tid >> 6, lane = tid & 63;
    const int wm = wid >> 2, wn = wid & 3;
    const int l15 = lane & 15, l4 = lane >> 4;
    const int sw = l15 & 7;
    constexpr int VT = NPASS * KTP;
    const size_t wstride = (size_t)KTP * 128;   // W row bytes

    auto stage = [&](int h) {
        const int t = h >> 2;
        if (t >= VT) return;
        const int m = h & 3;
        const int pass = t / KTP;
        const int k0b = (t - pass * KTP) << 7;
        char* ldsdst = smem + (size_t)(h & 7) * 16384;
        const char* src;
        size_t stride;
        if (m < 2) {
            src = Ab + (pass == 2 ? aloff : 0) + (size_t)(mt * 256 + m * 128) * astride + k0b;
            stride = (size_t)astride;
        } else {
            const bf16_t* wp = (pass == 1) ? Wl : Wh;
            src = (const char*)wp + (size_t)(nt * 256 + (m - 2) * 128) * wstride + k0b;
            stride = wstride;
        }
        const int r0 = tid >> 3, cd = tid & 7;
#pragma unroll
        for (int l = 0; l < 2; ++l) {
            const int row = l * 64 + r0;
            gload16(src + (size_t)row * stride + (size_t)((cd ^ (row & 7)) << 4),
                    ldsdst + l * 8192 + tid * 16);
        }
    };

    f32x4 acc[8][4];
#pragma unroll
    for (int i = 0; i < 8; ++i)
#pragma unroll
        for (int j = 0; j < 4; ++j) acc[i][j] = f32x4{0.f, 0.f, 0.f, 0.f};

    // prologue: tile0 all 4 halves + tile1 A-halves
#pragma unroll
    for (int h = 0; h < 6; ++h) stage(h);
    asm volatile("s_waitcnt vmcnt(4)" ::: "memory");
    __builtin_amdgcn_s_barrier();

    s16x8 a03[4][2], a47[4][2], bb[2][2];

    for (int vt = 0; vt < VT; ++vt) {
        const char* ldsA = smem + (vt & 1) * 65536 + wm * 16384;
        const char* ldsB = smem + (vt & 1) * 65536 + 32768 + (wn >> 1) * 16384;
        const int brb = (wn & 1) * 64;
        const int hb = vt * 4 + 6;

        // ---- phase 0
#pragma unroll
        for (int i = 0; i < 4; ++i) {
            const int row = i * 16 + l15;
#pragma unroll
            for (int kk = 0; kk < 2; ++kk)
                a03[i][kk] = *(const s16x8*)(ldsA + row * 128 + ((((kk << 2) | l4) ^ sw) << 4));
        }
#pragma unroll
        for (int j = 0; j < 2; ++j) {
            const int row = brb + j * 16 + l15;
#pragma unroll
            for (int kk = 0; kk < 2; ++kk)
                bb[j][kk] = *(const s16x8*)(ldsB + row * 128 + ((((kk << 2) | l4) ^ sw) << 4));
        }
        stage(hb + 0);
        __builtin_amdgcn_s_barrier();
        __builtin_amdgcn_s_setprio(1);
#pragma unroll
        for (int i = 0; i < 4; ++i)
#pragma unroll
            for (int j = 0; j < 2; ++j)
#pragma unroll
                for (int kk = 0; kk < 2; ++kk)
                    acc[i][j] = __builtin_amdgcn_mfma_f32_16x16x32_bf16(a03[i][kk], bb[j][kk], acc[i][j], 0, 0, 0);
        __builtin_amdgcn_s_setprio(0);
        __builtin_amdgcn_s_barrier();

        // ---- phase 1
#pragma unroll
        for (int i = 0; i < 4; ++i) {
            const int row = (4 + i) * 16 + l15;
#pragma unroll
            for (int kk = 0; kk < 2; ++kk)
                a47[i][kk] = *(const s16x8*)(ldsA + row * 128 + ((((kk << 2) | l4) ^ sw) << 4));
        }
        stage(hb + 1);
        __builtin_amdgcn_s_barrier();
        __builtin_amdgcn_s_setprio(1);
#pragma unroll
        for (int i = 0; i < 4; ++i)
#pragma unroll
            for (int j = 0; j < 2; ++j)
#pragma unroll
                for (int kk = 0; kk < 2; ++kk)
                    acc[4 + i][j] = __builtin_amdgcn_mfma_f32_16x16x32_bf16(a47[i][kk], bb[j][kk], acc[4 + i][j], 0, 0, 0);
        __builtin_amdgcn_s_setprio(0);
        __builtin_amdgcn_s_barrier();

        // ---- phase 2
#pragma unroll
        for (int j = 0; j < 2; ++j) {
            const int row = brb + (2 + j) * 16 + l15;
#pragma unroll
            for (int kk = 0; kk < 2; ++kk)
                bb[j][kk] = *(const s16x8*)(ldsB + row * 128 + ((((kk << 2) | l4) ^ sw) << 4));
        }
        stage(hb + 2);
        __builtin_amdgcn_s_barrier();
        __builtin_amdgcn_s_setprio(1);
#pragma unroll
        for (int i = 0; i < 4; ++i)
#pragma unroll
            for (int j = 0; j < 2; ++j)
#pragma unroll
                for (int kk = 0; kk < 2; ++kk)
                    acc[4 + i][2 + j] = __builtin_amdgcn_mfma_f32_16x16x32_bf16(a47[i][kk], bb[j][kk], acc[4 + i][2 + j], 0, 0, 0);
        __builtin_amdgcn_s_setprio(0);
        __builtin_amdgcn_s_barrier();

        // ---- phase 3 (register-only reads)
        stage(hb + 3);
        __builtin_amdgcn_s_barrier();
        __builtin_amdgcn_s_setprio(1);
#pragma unroll
        for (int i = 0; i < 4; ++i)
#pragma unroll
            for (int j = 0; j < 2; ++j)
#pragma unroll
                for (int kk = 0; kk < 2; ++kk)
                    acc[i][2 + j] = __builtin_amdgcn_mfma_f32_16x16x32_bf16(a03[i][kk], bb[j][kk], acc[i][2 + j], 0, 0, 0);
        __builtin_amdgcn_s_setprio(0);
        asm volatile("s_waitcnt vmcnt(4)" ::: "memory");
        __builtin_amdgcn_s_barrier();
    }

    // ---- epilogue ----
    const int grow0 = mt * 256 + wm * 128;
    const int gcol0 = nt * 256 + wn * 64;
#pragma unroll
    for (int i = 0; i < 8; ++i) {
#pragma unroll
        for (int j = 0; j < 4; ++j) {
            const int gcol = gcol0 + j * 16 + l15;
#pragma unroll
            for (int r = 0; r < 4; ++r) {
                const int grow = grow0 + i * 16 + l4 * 4 + r;
                float v = acc[i][j][r];
                if constexpr (MODE == 0) {
                    out0[(size_t)grow * ldout + gcol] = __float2bfloat16(v);
                } else if constexpr (MODE == 1) {
                    outf[(size_t)grow * ldout + gcol] = v;
                } else if constexpr (MODE == 2) {
                    const int seg = gcol / 768;          // uniform per block (768 % 256 == 0)
                    const int col = gcol - seg * 768;
                    const size_t oo = (size_t)grow * 768 + col;
                    if (seg == 0) {
                        out0[oo] = __float2bfloat16(v);  // skip (no bias)
                    } else {
                        v += bias[gcol - 768];
                        if (seg == 1)      p1[oo] = __float2bfloat16(1.f / (1.f + __expf(-v)));
                        else if (seg == 2) p2[oo] = __float2bfloat16(v);
                        else if (seg == 3) p3[oo] = __float2bfloat16(v * 0.10206207261596577f); // 1/sqrt(96)
                        else               p4[oo] = __float2bfloat16(v);
                    }
                } else {
                    const size_t oo = (size_t)grow * ldout + gcol;
                    outf[oo] = v + resid[oo];
                }
            }
        }
    }
}

// ================= chunkwise-parallel mLSTM recurrence =================
// ---- 1. gate scan: 1 block per batch b, 64 threads = 8 heads x 8 chunks ----
__global__ __launch_bounds__(64) void mscan_kernel(const float* __restrict__ gates,
                                                   float* __restrict__ wAo, float* __restrict__ go,
                                                   float* __restrict__ mprev, float* __restrict__ alpha) {
    const int b = blockIdx.x;
    const int lane = threadIdx.x;
    const int hd = lane >> 3, c = lane & 7;
    const size_t gbase = ((size_t)b * S_ + c * LCH) * 16;
    float F = 0.f, I = -1e30f;
    for (int t = 0; t < LCH; ++t) {
        const float fi = gates[gbase + t * 16 + hd];
        const float ff = gates[gbase + t * 16 + 8 + hd];
        I = fmaxf(I + ff, fi);
        F += ff;
    }
    float Fs = F, Is = I;
#pragma unroll
    for (int off = 1; off < 8; off <<= 1) {
        const float Fo = __shfl_up(Fs, off);
        const float Io = __shfl_up(Is, off);
        if (c >= off) { Is = fmaxf(Io + Fs, Is); Fs = Fo + Fs; }
    }
    const float Fe = __shfl_up(Fs, 1);
    const float Ie = __shfl_up(Is, 1);
    const float mp = (c == 0) ? 0.f : fmaxf(Fe, Ie);
    float m = mp; F = 0.f;
    const size_t wbase = ((size_t)(b * NH_ + hd)) * S_ + c * LCH;
    for (int t = 0; t < LCH; ++t) {
        const float fi = gates[gbase + t * 16 + hd];
        const float ff = gates[gbase + t * 16 + 8 + hd];
        F += ff;
        m = fmaxf(ff + m, fi);
        wAo[wbase + t] = fi - F;
        go[wbase + t] = F - m;
    }
    const int idx = (b * NH_ + hd) * NCH + c;
    mprev[idx] = mp;
    alpha[idx] = __expf(fminf(mp + F - m, 0.f));
}

// ---- 2. chunk summaries ----
__global__ __launch_bounds__(512) void chunkA_kernel(
    const bf16_t* __restrict__ kb, const bf16_t* __restrict__ vb,
    const float* __restrict__ wAo, const float* __restrict__ go,
    float* __restrict__ Bst) {
    const int c = blockIdx.x, bh = blockIdx.y;
    const int b = bh >> 3, hd = bh & 7;
    __shared__ bf16_t kT[96 * 136];
    __shared__ bf16_t vTh[96 * 136];
    __shared__ bf16_t vTl[96 * 136];
    __shared__ float coeffL[128];
    const int tid = threadIdx.x, lane = tid & 63, wid = tid >> 6;
    const int l15 = lane & 15, l4 = lane >> 4;
    const int s0 = c * LCH;
    const size_t seqb = (size_t)bh * S_;
    const float gend = go[seqb + s0 + LCH - 1];
    f32x4 acc[6];
#pragma unroll
    for (int nf = 0; nf < 6; ++nf) acc[nf] = f32x4{0.f, 0.f, 0.f, 0.f};
    float nacc = 0.f;
    const int ne = tid - 384;

    for (int sb = 0; sb < 2; ++sb) {
        __syncthreads();
        if (tid < 128) coeffL[tid] = __expf(fminf(wAo[seqb + s0 + sb * 128 + tid] + gend, 0.f));
        __syncthreads();
        {
            const int st = tid >> 2, e0 = (tid & 3) * 24;
            const size_t rowb = (size_t)(b * S_ + s0 + sb * 128 + st) * HID_ + hd * DH_ + e0;
            const float cf = coeffL[st];
#pragma unroll
            for (int jj = 0; jj < 3; ++jj) {
                const u16x8 kv = *(const u16x8*)(kb + rowb + jj * 8);
                const u16x8 vv = *(const u16x8*)(vb + rowb + jj * 8);
#pragma unroll
                for (int u = 0; u < 8; ++u) {
                    const int e = e0 + jj * 8 + u;
                    kT[e * 136 + st] = u2b(kv[u]);
                    const float vf = b2f(vv[u]) * cf;
                    const bf16_t hh = __float2bfloat16(vf);
                    vTh[e * 136 + st] = hh;
                    vTl[e * 136 + st] = __float2bfloat16(vf - __bfloat162float(hh));
                }
            }
        }
        __syncthreads();
        if (wid < 6) {
#pragma unroll
            for (int pass = 0; pass < 2; ++pass) {
                const bf16_t* Ap = pass ? vTl : vTh;
#pragma unroll
                for (int ks = 0; ks < 4; ++ks) {
                    const s16x8 af = *(const s16x8*)((const char*)Ap + (wid * 16 + l15) * 272 + ks * 64 + l4 * 16);
#pragma unroll
                    for (int nf = 0; nf < 6; ++nf) {
                        const s16x8 bf = *(const s16x8*)((const char*)kT + (nf * 16 + l15) * 272 + ks * 64 + l4 * 16);
                        acc[nf] = __builtin_amdgcn_mfma_f32_16x16x32_bf16(af, bf, acc[nf], 0, 0, 0);
                    }
                }
            }
        } else if (ne < 96) {
            for (int sg = 0; sg < 128; ++sg)
                nacc += coeffL[sg] * __bfloat162float(kT[ne * 136 + sg]);
        }
    }
    float* outp = Bst + ((size_t)bh * NCH + c) * 9312;
    if (wid < 6) {
#pragma unroll
        for (int nf = 0; nf < 6; ++nf)
#pragma unroll
            for (int r = 0; r < 4; ++r)
                outp[(size_t)(wid * 16 + l4 * 4 + r) * 96 + nf * 16 + l15] = acc[nf][r];
    } else if (ne < 96) {
        outp[9216 + ne] = nacc;
    }
}

// ---- 3. inter-chunk scan, in-place ----
__global__ __launch_bounds__(96) void chunkB_kernel(float* __restrict__ Bst,
                                                    const float* __restrict__ alpha) {
    const int idx = blockIdx.x * 96 + threadIdx.x;
    const int bh = blockIdx.y;
    float val = (idx < 9216) ? 0.f : 1.f;
    for (int c = 0; c < NCH; ++c) {
        float* p = Bst + ((size_t)bh * NCH + c) * 9312 + idx;
        const float t = *p;
        *p = val;
        val = alpha[bh * NCH + c] * val + t;
    }
}

// ---- 4. outputs ----
__global__ __launch_bounds__(256) void chunkC_kernel(
    const bf16_t* __restrict__ qb, const bf16_t* __restrict__ kb,
    const bf16_t* __restrict__ vb, const bf16_t* __restrict__ ob,
    const float* __restrict__ wAo, const float* __restrict__ go,
    const float* __restrict__ mprev, const float* __restrict__ Cst,
    float* __restrict__ hb) {
    const int c = blockIdx.x >> 2, qblk = blockIdx.x & 3;
    const int bh = blockIdx.y, b = bh >> 3, hd = bh & 7;
    __shared__ bf16_t Qs[64 * 104];
    __shared__ bf16_t Ks[64 * 104];
    __shared__ bf16_t vTs[112 * 72];
    __shared__ bf16_t Phs[64 * 72];
    __shared__ bf16_t Pls[64 * 72];
    __shared__ bf16_t CsH[112 * 104];
    __shared__ bf16_t CsL[112 * 104];
    __shared__ float wAL[256];
    __shared__ float gL[64];
    __shared__ float scL[64];
    const int tid = threadIdx.x, lane = tid & 63, wid = tid >> 6;
    const int l15 = lane & 15, l4 = lane >> 4;
    const int s0 = c * LCH;
    const size_t seqb = (size_t)bh * S_;
    const int tq0 = b * S_ + s0 + qblk * 64;

    wAL[tid] = wAo[seqb + s0 + tid];
    if (tid < 64) {
        const float gg = go[seqb + s0 + qblk * 64 + tid];
        gL[tid] = gg;
        scL[tid] = __expf(fminf(mprev[bh * NCH + c] + gg, 0.f));
    }
    {
        const int tt = tid >> 2, e0 = (tid & 3) * 24;
        const bf16_t* qrow = qb + (size_t)(tq0 + tt) * HID_ + hd * DH_ + e0;
#pragma unroll
        for (int jj = 0; jj < 3; ++jj)
            *(u16x8*)&Qs[tt * 104 + e0 + jj * 8] = *(const u16x8*)(qrow + jj * 8);
    }
    {
        const float* Csp = Cst + ((size_t)bh * NCH + c) * 9312;
        for (int i = tid; i < 9312; i += 256) {
            int dd, ee;
            if (i < 9216) { dd = i / 96; ee = i - dd * 96; }
            else          { dd = 96;     ee = i - 9216; }
            const float xv = Csp[i];
            const bf16_t hh = __float2bfloat16(xv);
            CsH[dd * 104 + ee] = hh;
            CsL[dd * 104 + ee] = __float2bfloat16(xv - __bfloat162float(hh));
        }
        const bf16_t z16 = __float2bfloat16(0.f);
        for (int i = tid; i < 15 * 104; i += 256) { CsH[97 * 104 + i] = z16; CsL[97 * 104 + i] = z16; }
        if (tid < 64) vTs[96 * 72 + tid] = __float2bfloat16(1.f);
        for (int i = tid; i < 15 * 72; i += 256) vTs[97 * 72 + i] = z16;
    }
    __syncthreads();

    f32x4 acc[7];
#pragma unroll
    for (int nf = 0; nf < 7; ++nf) acc[nf] = f32x4{0.f, 0.f, 0.f, 0.f};
#pragma unroll
    for (int pass = 0; pass < 2; ++pass) {
        const bf16_t* Cp = pass ? CsL : CsH;
#pragma unroll
        for (int ks = 0; ks < 3; ++ks) {
            const s16x8 af = *(const s16x8*)((const char*)Qs + (wid * 16 + l15) * 208 + ks * 64 + l4 * 16);
#pragma unroll
            for (int nf = 0; nf < 7; ++nf) {
                const s16x8 bf = *(const s16x8*)((const char*)Cp + (nf * 16 + l15) * 208 + ks * 64 + l4 * 16);
                acc[nf] = __builtin_amdgcn_mfma_f32_16x16x32_bf16(af, bf, acc[nf], 0, 0, 0);
            }
        }
    }
    {
        float scr[4];
#pragma unroll
        for (int r = 0; r < 4; ++r) scr[r] = scL[wid * 16 + l4 * 4 + r];
#pragma unroll
        for (int nf = 0; nf < 7; ++nf)
#pragma unroll
            for (int r = 0; r < 4; ++r) acc[nf][r] *= scr[r];
    }

    for (int sb = 0; sb <= qblk; ++sb) {
        __syncthreads();
        {
            const int tt = tid >> 2, e0 = (tid & 3) * 24;
            const size_t rowb = (size_t)(b * S_ + s0 + sb * 64 + tt) * HID_ + hd * DH_ + e0;
#pragma unroll
            for (int jj = 0; jj < 3; ++jj) {
                *(u16x8*)&Ks[tt * 104 + e0 + jj * 8] = *(const u16x8*)(kb + rowb + jj * 8);
                const u16x8 vv = *(const u16x8*)(vb + rowb + jj * 8);
#pragma unroll
                for (int u = 0; u < 8; ++u)
                    vTs[(e0 + jj * 8 + u) * 72 + tt] = u2b(vv[u]);
            }
        }
        __syncthreads();
        f32x4 pacc[4];
#pragma unroll
        for (int nf = 0; nf < 4; ++nf) pacc[nf] = f32x4{0.f, 0.f, 0.f, 0.f};
#pragma unroll
        for (int ks = 0; ks < 3; ++ks) {
            const s16x8 af = *(const s16x8*)((const char*)Qs + (wid * 16 + l15) * 208 + ks * 64 + l4 * 16);
#pragma unroll
            for (int nf = 0; nf < 4; ++nf) {
                const s16x8 bf = *(const s16x8*)((const char*)Ks + (nf * 16 + l15) * 208 + ks * 64 + l4 * 16);
                pacc[nf] = __builtin_amdgcn_mfma_f32_16x16x32_bf16(af, bf, pacc[nf], 0, 0, 0);
            }
        }
#pragma unroll
        for (int nf = 0; nf < 4; ++nf) {
#pragma unroll
            for (int r = 0; r < 4; ++r) {
                const int tr = wid * 16 + l4 * 4 + r;
                const int sg = nf * 16 + l15;
                float p = 0.f;
                if (sb < qblk || sg <= tr)
                    p = pacc[nf][r] * __expf(fminf(wAL[sb * 64 + sg] + gL[tr], 0.f));
                const bf16_t hh = __float2bfloat16(p);
                Phs[tr * 72 + sg] = hh;
                Pls[tr * 72 + sg] = __float2bfloat16(p - __bfloat162float(hh));
            }
        }
        __syncthreads();
#pragma unroll
        for (int pass = 0; pass < 2; ++pass) {
            const bf16_t* Pp = pass ? Pls : Phs;
#pragma unroll
            for (int ks = 0; ks < 2; ++ks) {
                const s16x8 af = *(const s16x8*)((const char*)Pp + (wid * 16 + l15) * 144 + ks * 64 + l4 * 16);
#pragma unroll
                for (int nf = 0; nf < 7; ++nf) {
                    const s16x8 bf = *(const s16x8*)((const char*)vTs + (nf * 16 + l15) * 144 + ks * 64 + l4 * 16);
                    acc[nf] = __builtin_amdgcn_mfma_f32_16x16x32_bf16(af, bf, acc[nf], 0, 0, 0);
                }
            }
        }
    }

#pragma unroll
    for (int r = 0; r < 4; ++r) {
        float den = __shfl(acc[6][r], lane & 48);
        den = fmaxf(den, 1.0f);
        const int tr = wid * 16 + l4 * 4 + r;
        const size_t rowb = (size_t)(tq0 + tr) * HID_ + hd * DH_;
#pragma unroll
        for (int nf = 0; nf < 6; ++nf) {
            const int dc = nf * 16 + l15;
            const float o = __bfloat162float(ob[rowb + dc]);
            hb[rowb + dc] = o * acc[nf][r] / den;
        }
    }
}

// ---------------- (LN(h)+skip)*silu(r) -> compact bf16 pre [T,768] ----------------
__global__ __launch_bounds__(256) void epi1_kernel(const float* __restrict__ h,
                                                   const bf16_t* __restrict__ xskip,
                                                   const bf16_t* __restrict__ r,
                                                   const float* __restrict__ hw,
                                                   const float* __restrict__ hbi,
                                                   bf16_t* __restrict__ pre) {
    const int t = blockIdx.x, tid = threadIdx.x;
    const size_t rb = (size_t)t * HID_;
    float v0 = h[rb + tid], v1 = h[rb + tid + 256], v2 = h[rb + tid + 512];
    float sm = v0 + v1 + v2;
    float sq = v0 * v0 + v1 * v1 + v2 * v2;
#pragma unroll
    for (int off = 32; off > 0; off >>= 1) { sm += __shfl_xor(sm, off); sq += __shfl_xor(sq, off); }
    __shared__ float ws4[8];
    const int wid = tid >> 6, lane = tid & 63;
    if (lane == 0) { ws4[wid] = sm; ws4[4 + wid] = sq; }
    __syncthreads();
    sm = ws4[0] + ws4[1] + ws4[2] + ws4[3];
    sq = ws4[4] + ws4[5] + ws4[6] + ws4[7];
    const float mu = sm * (1.f / HID_);
    const float rs = rsqrtf(sq * (1.f / HID_) - mu * mu + 1e-6f);
    bf16_t* row = pre + (size_t)t * HID_;
#pragma unroll
    for (int k2 = 0; k2 < 3; ++k2) {
        const int c = tid + k2 * 256;
        const float v = (k2 == 0 ? v0 : k2 == 1 ? v1 : v2);
        float o = (v - mu) * rs * hw[c] + hbi[c] + __bfloat162float(xskip[rb + c]);
        const float rv = __bfloat162float(r[rb + c]);
        o *= rv * (1.f / (1.f + __expf(-rv)));
        row[c] = __float2bfloat16(o);
    }
}

extern "C" void kernel_launch(void* const* d_in, const int* in_sizes, int n_in,
                              void* d_out, int out_size, void* d_ws, size_t ws_size,
                              hipStream_t stream) {
    const float* x      = (const float*)d_in[0];
    const float* ln_w   = (const float*)d_in[1];
    const float* ln_b   = (const float*)d_in[2];
    const float* up_l_w = (const float*)d_in[3];
    const float* up_r_w = (const float*)d_in[4];
    const float* conv_w = (const float*)d_in[5];
    const float* skip_w = (const float*)d_in[6];
    const float* fused_w= (const float*)d_in[7];
    const float* fused_b= (const float*)d_in[8];
    const float* hid_w  = (const float*)d_in[9];
    const float* hid_b  = (const float*)d_in[10];
    const float* down_w = (const float*)d_in[11];
    float* out = (float*)d_out;
    (void)n_in; (void)out_size; (void)ws_size;

    const size_t T = (size_t)in_sizes[0] / D_;   // 16384
    const int B = (int)(T / S_);                 // 8

    // ---- workspace layout: ~223.7 MB total (< proven-safe 231.9 MB) ----
    char* ws = (char*)d_ws;
    size_t off = 0;
    auto take = [&](size_t bytes) -> char* {
        char* p = ws + off; off = (off + bytes + 255) & ~(size_t)255; return p;
    };
    // recurrence arena; the up/cat weights alias inside (dead before recurrence)
    char* arena = take(20123904);
    bf16_t* wul_h = (bf16_t*)(arena);                       // 2,359,296 B
    bf16_t* wul_l = (bf16_t*)(arena + 2359296);             // 2,359,296 B
    bf16_t* wur   = (bf16_t*)(arena + 4718592);             // 1,179,648 B
    bf16_t* wcat  = (bf16_t*)(arena + 5898240);             // [3840,1536] = 11,796,480 B (ends 17.7MB)
    float* Bst    = (float*)(arena);                        // 19,070,976 B
    float* wAarr  = (float*)(arena + 19071232);
    float* garr   = (float*)(arena + 19595520);
    float* mprevA = (float*)(arena + 20119808);
    float* alphaA = (float*)(arena + 20121856);

    bf16_t* wdn_h = (bf16_t*)take((size_t)D_ * HID_ * 2);   // survives until final GEMM
    char*   xnreg = take(T * 1536 * 2);   // ln hi/lo -> compact xc-hi plane -> h fp32
    char*   big   = take(T * 1536 * 4);   // xl fp32 -> [o|q|k|v] bf16 -> pre bf16
    bf16_t* rbuf  = (bf16_t*)take(T * HID_ * 2);
    bf16_t* skipb = (bf16_t*)take(T * HID_ * 2);
    float*  gates = (float*)take(T * 16 * 4);

    bf16_t* xn   = (bf16_t*)xnreg;
    bf16_t* xch  = (bf16_t*)xnreg;
    float*  h    = (float*)xnreg;
    float*  xl   = (float*)big;
    bf16_t* obuf = (bf16_t*)big;
    bf16_t* qbuf = (bf16_t*)(big + T * HID_ * 2);
    bf16_t* kbuf = (bf16_t*)(big + T * HID_ * 4);
    bf16_t* vbuf = (bf16_t*)(big + T * HID_ * 6);
    bf16_t* pre  = (bf16_t*)big;          // compact [T,768] (over o,q; dead)

    const int MT = (int)(T / 256);   // 64

    // 1. weight conversions: up_l split; up_r; [skip | fused] concatenated; down hi-only
    cvt2_kernel<<<512, 256, 0, stream>>>(up_l_w, wul_h, wul_l, P_ * D_);
    cvt_kernel <<<512, 256, 0, stream>>>(up_r_w, wur, HID_ * D_);
    cvt_kernel <<<512, 256, 0, stream>>>(skip_w, wcat, HID_ * P_);
    cvt_kernel <<<2048, 256, 0, stream>>>(fused_w + (size_t)16 * P_, wcat + (size_t)HID_ * P_, 3072 * P_);
    cvt_kernel <<<512, 256, 0, stream>>>(down_w, wdn_h, D_ * HID_);
    // 2. LayerNorm -> xn hi/lo
    ln_x_kernel<<<(int)T, 256, 0, stream>>>(x, ln_w, ln_b, xn);
    // 3. xl = xn @ up_l^T (3-pass split, fp32 out; protects the gate path)  K=768
    gemm256<3, 1, 12><<<dim3(P_ / 256, MT), 512, 0, stream>>>(
        (const char*)xn, 3072, 1536, wul_h, wul_l,
        nullptr, xl, P_, nullptr, nullptr, nullptr, nullptr, nullptr, nullptr);
    // 4. r = xn_hi @ up_r^T (1-pass)
    gemm256<1, 0, 12><<<dim3(HID_ / 256, MT), 512, 0, stream>>>(
        (const char*)xn, 3072, 0, wur, nullptr,
        rbuf, nullptr, HID_, nullptr, nullptr, nullptr, nullptr, nullptr, nullptr);
    // 5. conv+silu -> compact xc-hi plane; exact fp32 gates fused in
    conv_gate_kernel<<<(int)T, 192, 0, stream>>>(xl, conv_w, fused_w, fused_b, xch, gates);
    // 6. merged [skip | o,q,k,v] = xc_hi @ wcat^T (1-pass, N=3840)  K=1536
    gemm256<1, 2, 24><<<dim3(3840 / 256, MT), 512, 0, stream>>>(
        (const char*)xch, 3072, 0, wcat, nullptr,
        skipb, nullptr, 0, obuf, qbuf, kbuf, vbuf, fused_b + 16, nullptr);
    // 7. chunkwise-parallel recurrence -> h fp32 (arena weights dead now)
    mscan_kernel<<<B, 64, 0, stream>>>(gates, wAarr, garr, mprevA, alphaA);
    chunkA_kernel<<<dim3(NCH, B * NH_), 512, 0, stream>>>(kbuf, vbuf, wAarr, garr, Bst);
    chunkB_kernel<<<dim3(97, B * NH_), 96, 0, stream>>>(Bst, alphaA);
    chunkC_kernel<<<dim3(NCH * 4, B * NH_), 256, 0, stream>>>(qbuf, kbuf, vbuf, obuf,
                                                              wAarr, garr, mprevA, Bst, h);
    // 8. (LN(h)+skip)*silu(r) -> compact pre
    epi1_kernel<<<(int)T, 256, 0, stream>>>(h, skipb, rbuf, hid_w, hid_b, pre);
    // 9. out = pre @ down^T + x (1-pass)  K=768
    gemm256<1, 3, 12><<<dim3(HID_ / 256, MT), 512, 0, stream>>>(
        (const char*)pre, 1536, 0, wdn_h, nullptr,
        nullptr, out, HID_, nullptr, nullptr, nullptr, nullptr, nullptr, x);
}

// Round 7
// 721.431 us; speedup vs baseline: 5.2130x; 1.1402x over previous
//
#include <hip/hip_runtime.h>
#include <hip/hip_bf16.h>

#define D_    768
#define P_    1536
#define HID_  768
#define NH_   8
#define DH_   96
#define S_    2048
#define LCH   256     // recurrence chunk length
#define NCH   8       // chunks per sequence

typedef __hip_bfloat16 bf16_t;
typedef __attribute__((ext_vector_type(8))) short s16x8;
typedef __attribute__((ext_vector_type(8))) unsigned short u16x8;
typedef __attribute__((ext_vector_type(4))) float f32x4;

__device__ __forceinline__ float b2f(unsigned short u) {
    union { unsigned int i; float f; } x; x.i = ((unsigned int)u) << 16; return x.f;
}
__device__ __forceinline__ unsigned short f2b(float f) {
    bf16_t h = __float2bfloat16(f);
    unsigned short u; __builtin_memcpy(&u, &h, 2); return u;
}
__device__ __forceinline__ bf16_t u2b(unsigned short u) {
    bf16_t t; __builtin_memcpy(&t, &u, 2); return t;
}

// async global->LDS, 16B per lane (LDS dest = wave-uniform base + lane*16, linear layout)
__device__ __forceinline__ void gload16(const void* g, const void* l) {
    __builtin_amdgcn_global_load_lds(
        (const __attribute__((address_space(1))) unsigned int*)(unsigned long long)(g),
        (__attribute__((address_space(3))) unsigned int*)(unsigned int)(unsigned long long)(l),
        16, 0, 0);
}

// ---------------- all weight conversions in one grid-stride kernel ----------------
// region A: [up_l | up_r] -> win hi/lo split (2304 x 768)
// region B: [skip | fused[16:]] -> wcat hi (3840 x 1536)
// region C: down -> wdn hi (768 x 768)
__global__ void cvt_all_kernel(const float* __restrict__ up_l_w, const float* __restrict__ up_r_w,
                               const float* __restrict__ skip_w, const float* __restrict__ fused_w,
                               const float* __restrict__ down_w,
                               bf16_t* __restrict__ win_h, bf16_t* __restrict__ win_l,
                               bf16_t* __restrict__ wcat, bf16_t* __restrict__ wdn) {
    const int N1 = 2304 * 768, N2 = 3840 * 1536, N3 = 768 * 768;
    int i = blockIdx.x * blockDim.x + threadIdx.x;
    const int stride = gridDim.x * blockDim.x;
    for (; i < N1 + N2 + N3; i += stride) {
        if (i < N1) {
            const float x = (i < 1536 * 768) ? up_l_w[i] : up_r_w[i - 1536 * 768];
            const bf16_t h = __float2bfloat16(x);
            win_h[i] = h;
            win_l[i] = __float2bfloat16(x - __bfloat162float(h));
        } else if (i < N1 + N2) {
            const int j = i - N1;
            const float x = (j < 768 * 1536) ? skip_w[j] : fused_w[16 * 1536 + (j - 768 * 1536)];
            wcat[j] = __float2bfloat16(x);
        } else {
            wdn[i - N1 - N2] = __float2bfloat16(down_w[i - N1 - N2]);
        }
    }
}

// ---------------- LayerNorm(x) -> compact bf16 [T,768] ----------------
__global__ __launch_bounds__(256) void ln_x_kernel(const float* __restrict__ x,
                                                   const float* __restrict__ w,
                                                   const float* __restrict__ b,
                                                   bf16_t* __restrict__ xn) {
    const int t = blockIdx.x, tid = threadIdx.x;
    const size_t rb = (size_t)t * D_;
    float v0 = x[rb + tid], v1 = x[rb + tid + 256], v2 = x[rb + tid + 512];
    float sm = v0 + v1 + v2;
    float sq = v0 * v0 + v1 * v1 + v2 * v2;
#pragma unroll
    for (int off = 32; off > 0; off >>= 1) { sm += __shfl_xor(sm, off); sq += __shfl_xor(sq, off); }
    __shared__ float ws4[8];
    const int wid = tid >> 6, lane = tid & 63;
    if (lane == 0) { ws4[wid] = sm; ws4[4 + wid] = sq; }
    __syncthreads();
    sm = ws4[0] + ws4[1] + ws4[2] + ws4[3];
    sq = ws4[4] + ws4[5] + ws4[6] + ws4[7];
    const float mu = sm * (1.f / D_);
    const float rs = rsqrtf(sq * (1.f / D_) - mu * mu + 1e-6f);
    bf16_t* row = xn + rb;
#pragma unroll
    for (int k2 = 0; k2 < 3; ++k2) {
        const int c = tid + k2 * 256;
        const float v = (k2 == 0 ? v0 : k2 == 1 ? v1 : v2);
        row[c] = __float2bfloat16((v - mu) * rs * w[c] + b[c]);
    }
}

// ---------------- conv(K=4)+SiLU from fp32 xl; writes compact xc-hi plane; fp32 gates fused ----------------
__global__ __launch_bounds__(192) void conv_gate_kernel(const float* __restrict__ xl,
                                                        const float* __restrict__ cw,
                                                        const float* __restrict__ fw,
                                                        const float* __restrict__ fb,
                                                        bf16_t* __restrict__ xch,
                                                        float* __restrict__ gates) {
    const int t = blockIdx.x, c = threadIdx.x;   // c: 8-float chunk, 192*8 = 1536
    const float* row = xl + (size_t)t * P_;
    const float4* r4 = (const float4*)row;
    float4 a = r4[2 * c], b4 = r4[2 * c + 1];
    float pm3 = 0.f, pm2 = 0.f, pm1 = 0.f;
    if (c > 0) { pm3 = row[c * 8 - 3]; pm2 = row[c * 8 - 2]; pm1 = row[c * 8 - 1]; }
    const float w0 = cw[0], w1 = cw[1], w2 = cw[2], w3 = cw[3];
    float xv[11] = {pm3, pm2, pm1, a.x, a.y, a.z, a.w, b4.x, b4.y, b4.z, b4.w};
    float xc[8];
    u16x8 h8;
#pragma unroll
    for (int j = 0; j < 8; ++j) {
        float s = w0 * xv[j] + w1 * xv[j + 1] + w2 * xv[j + 2] + w3 * xv[j + 3];
        s = s * (1.f / (1.f + __expf(-s)));   // SiLU
        xc[j] = s;
        h8[j] = f2b(s);
    }
    *(u16x8*)(xch + (size_t)t * P_ + c * 8) = h8;

    // fused exact-fp32 gate dots: z_j = sum_p xc_p * fw[j*1536+p], j = 0..15
    float pj[16];
#pragma unroll
    for (int j = 0; j < 16; ++j) {
        const float* wr = fw + (size_t)j * P_ + c * 8;
        float p = 0.f;
#pragma unroll
        for (int u = 0; u < 8; ++u) p += xc[u] * wr[u];
        pj[j] = p;
    }
#pragma unroll
    for (int j = 0; j < 16; ++j)
#pragma unroll
        for (int off = 32; off > 0; off >>= 1) pj[j] += __shfl_xor(pj[j], off);
    __shared__ float red[3][16];
    const int wv = c >> 6, ln = c & 63;
    if (ln == 0) {
#pragma unroll
        for (int j = 0; j < 16; ++j) red[wv][j] = pj[j];
    }
    __syncthreads();
    if (c < 16) {
        const float z = red[0][c] + red[1][c] + red[2][c] + fb[c];
        gates[(size_t)t * 16 + c] = 15.f * tanhf(z * (1.f / 15.f));
    }
}

// ============== 256x256 8-phase pipelined bf16 MFMA GEMM, C = A[M,K] * W[N,K]^T ==============
// Virtual K-tile stream folds precision passes: pass 0: Ah*Wh; 1: Ah*Wl; 2: (A+aloff)*Wh.
// 8 waves (2M x 4N), per-wave 128x64, BK=64, LDS = 8 half-tile slots x 16KB (128KB dbuf).
// Swizzle: linear LDS dest, global source chunk ^= row&7, ds_read chunk ^= row&7.
// vmcnt(4) once per tile (never 0 in the loop). Bijective XCD swizzle (requires nwg % 8 == 0).
// MODE 0: bf16 out0. MODE 1: fp32 outf.
// MODE 2 (merged skip+qkvo, N=3840): seg0 skip->out0 (no bias); seg1 sigmoid->p1;
//         seg2 q->p2; seg3 k/sqrt(96)->p3; seg4 v->p4 (bias = fused_b+16 at gcol-768).
// MODE 3: fp32 outf = acc + resid.
// MODE 4 (merged up, N=2304): cols<1536 -> fp32 xl (outf); cols>=1536 -> bf16 r (out0).
template <int NPASS, int MODE, int KTP>
__global__ __launch_bounds__(512, 2) void gemm256(
    const char* __restrict__ Ab, int astride, int aloff,
    const bf16_t* __restrict__ Wh, const bf16_t* __restrict__ Wl,
    bf16_t* __restrict__ out0, float* __restrict__ outf, int ldout,
    bf16_t* __restrict__ p1, bf16_t* __restrict__ p2,
    bf16_t* __restrict__ p3, bf16_t* __restrict__ p4,
    const float* __restrict__ bias, const float* __restrict__ resid) {
    __shared__ char smem[131072];
    const int tid = threadIdx.x;
    // bijective XCD-aware chunked swizzle (nwg % 8 == 0 guaranteed by launch)
    const int gx = gridDim.x;
    int flat = blockIdx.y * gx + blockIdx.x;
    const int cpx = (gx * gridDim.y) >> 3;
    flat = (flat & 7) * cpx + (flat >> 3);
    const int nt = flat % gx, mt = flat / gx;
    const int wid = tid >> 6, lane = tid & 63;
    const int wm = wid >> 2, wn = wid & 3;
    const int l15 = lane & 15, l4 = lane >> 4;
    const int sw = l15 & 7;
    constexpr int VT = NPASS * KTP;
    const size_t wstride = (size_t)KTP * 128;   // W row bytes

    auto stage = [&](int h) {
        const int t = h >> 2;
        if (t >= VT) return;
        const int m = h & 3;
        const int pass = t / KTP;
        const int k0b = (t - pass * KTP) << 7;
        char* ldsdst = smem + (size_t)(h & 7) * 16384;
        const char* src;
        size_t stride;
        if (m < 2) {
            src = Ab + (pass == 2 ? aloff : 0) + (size_t)(mt * 256 + m * 128) * astride + k0b;
            stride = (size_t)astride;
        } else {
            const bf16_t* wp = (pass == 1) ? Wl : Wh;
            src = (const char*)wp + (size_t)(nt * 256 + (m - 2) * 128) * wstride + k0b;
            stride = wstride;
        }
        const int r0 = tid >> 3, cd = tid & 7;
#pragma unroll
        for (int l = 0; l < 2; ++l) {
            const int row = l * 64 + r0;
            gload16(src + (size_t)row * stride + (size_t)((cd ^ (row & 7)) << 4),
                    ldsdst + l * 8192 + tid * 16);
        }
    };

    f32x4 acc[8][4];
#pragma unroll
    for (int i = 0; i < 8; ++i)
#pragma unroll
        for (int j = 0; j < 4; ++j) acc[i][j] = f32x4{0.f, 0.f, 0.f, 0.f};

    // prologue: tile0 all 4 halves + tile1 A-halves
#pragma unroll
    for (int h = 0; h < 6; ++h) stage(h);
    asm volatile("s_waitcnt vmcnt(4)" ::: "memory");
    __builtin_amdgcn_s_barrier();

    s16x8 a03[4][2], a47[4][2], bb[2][2];

    for (int vt = 0; vt < VT; ++vt) {
        const char* ldsA = smem + (vt & 1) * 65536 + wm * 16384;
        const char* ldsB = smem + (vt & 1) * 65536 + 32768 + (wn >> 1) * 16384;
        const int brb = (wn & 1) * 64;
        const int hb = vt * 4 + 6;

        // ---- phase 0
#pragma unroll
        for (int i = 0; i < 4; ++i) {
            const int row = i * 16 + l15;
#pragma unroll
            for (int kk = 0; kk < 2; ++kk)
                a03[i][kk] = *(const s16x8*)(ldsA + row * 128 + ((((kk << 2) | l4) ^ sw) << 4));
        }
#pragma unroll
        for (int j = 0; j < 2; ++j) {
            const int row = brb + j * 16 + l15;
#pragma unroll
            for (int kk = 0; kk < 2; ++kk)
                bb[j][kk] = *(const s16x8*)(ldsB + row * 128 + ((((kk << 2) | l4) ^ sw) << 4));
        }
        stage(hb + 0);
        __builtin_amdgcn_s_barrier();
        __builtin_amdgcn_s_setprio(1);
#pragma unroll
        for (int i = 0; i < 4; ++i)
#pragma unroll
            for (int j = 0; j < 2; ++j)
#pragma unroll
                for (int kk = 0; kk < 2; ++kk)
                    acc[i][j] = __builtin_amdgcn_mfma_f32_16x16x32_bf16(a03[i][kk], bb[j][kk], acc[i][j], 0, 0, 0);
        __builtin_amdgcn_s_setprio(0);
        __builtin_amdgcn_s_barrier();

        // ---- phase 1
#pragma unroll
        for (int i = 0; i < 4; ++i) {
            const int row = (4 + i) * 16 + l15;
#pragma unroll
            for (int kk = 0; kk < 2; ++kk)
                a47[i][kk] = *(const s16x8*)(ldsA + row * 128 + ((((kk << 2) | l4) ^ sw) << 4));
        }
        stage(hb + 1);
        __builtin_amdgcn_s_barrier();
        __builtin_amdgcn_s_setprio(1);
#pragma unroll
        for (int i = 0; i < 4; ++i)
#pragma unroll
            for (int j = 0; j < 2; ++j)
#pragma unroll
                for (int kk = 0; kk < 2; ++kk)
                    acc[4 + i][j] = __builtin_amdgcn_mfma_f32_16x16x32_bf16(a47[i][kk], bb[j][kk], acc[4 + i][j], 0, 0, 0);
        __builtin_amdgcn_s_setprio(0);
        __builtin_amdgcn_s_barrier();

        // ---- phase 2
#pragma unroll
        for (int j = 0; j < 2; ++j) {
            const int row = brb + (2 + j) * 16 + l15;
#pragma unroll
            for (int kk = 0; kk < 2; ++kk)
                bb[j][kk] = *(const s16x8*)(ldsB + row * 128 + ((((kk << 2) | l4) ^ sw) << 4));
        }
        stage(hb + 2);
        __builtin_amdgcn_s_barrier();
        __builtin_amdgcn_s_setprio(1);
#pragma unroll
        for (int i = 0; i < 4; ++i)
#pragma unroll
            for (int j = 0; j < 2; ++j)
#pragma unroll
                for (int kk = 0; kk < 2; ++kk)
                    acc[4 + i][2 + j] = __builtin_amdgcn_mfma_f32_16x16x32_bf16(a47[i][kk], bb[j][kk], acc[4 + i][2 + j], 0, 0, 0);
        __builtin_amdgcn_s_setprio(0);
        __builtin_amdgcn_s_barrier();

        // ---- phase 3 (register-only reads)
        stage(hb + 3);
        __builtin_amdgcn_s_barrier();
        __builtin_amdgcn_s_setprio(1);
#pragma unroll
        for (int i = 0; i < 4; ++i)
#pragma unroll
            for (int j = 0; j < 2; ++j)
#pragma unroll
                for (int kk = 0; kk < 2; ++kk)
                    acc[i][2 + j] = __builtin_amdgcn_mfma_f32_16x16x32_bf16(a03[i][kk], bb[j][kk], acc[i][2 + j], 0, 0, 0);
        __builtin_amdgcn_s_setprio(0);
        asm volatile("s_waitcnt vmcnt(4)" ::: "memory");
        __builtin_amdgcn_s_barrier();
    }

    // ---- epilogue ----
    const int grow0 = mt * 256 + wm * 128;
    const int gcol0 = nt * 256 + wn * 64;
#pragma unroll
    for (int i = 0; i < 8; ++i) {
#pragma unroll
        for (int j = 0; j < 4; ++j) {
            const int gcol = gcol0 + j * 16 + l15;
#pragma unroll
            for (int r = 0; r < 4; ++r) {
                const int grow = grow0 + i * 16 + l4 * 4 + r;
                float v = acc[i][j][r];
                if constexpr (MODE == 0) {
                    out0[(size_t)grow * ldout + gcol] = __float2bfloat16(v);
                } else if constexpr (MODE == 1) {
                    outf[(size_t)grow * ldout + gcol] = v;
                } else if constexpr (MODE == 2) {
                    const int seg = gcol / 768;          // uniform per block (768 % 256 == 0)
                    const int col = gcol - seg * 768;
                    const size_t oo = (size_t)grow * 768 + col;
                    if (seg == 0) {
                        out0[oo] = __float2bfloat16(v);  // skip (no bias)
                    } else {
                        v += bias[gcol - 768];
                        if (seg == 1)      p1[oo] = __float2bfloat16(1.f / (1.f + __expf(-v)));
                        else if (seg == 2) p2[oo] = __float2bfloat16(v);
                        else if (seg == 3) p3[oo] = __float2bfloat16(v * 0.10206207261596577f); // 1/sqrt(96)
                        else               p4[oo] = __float2bfloat16(v);
                    }
                } else if constexpr (MODE == 3) {
                    const size_t oo = (size_t)grow * ldout + gcol;
                    outf[oo] = v + resid[oo];
                } else {   // MODE 4: merged up (xl fp32 | r bf16)
                    if (gcol < 1536) outf[(size_t)grow * 1536 + gcol] = v;
                    else             out0[(size_t)grow * 768 + (gcol - 1536)] = __float2bfloat16(v);
                }
            }
        }
    }
}

// ================= chunkwise-parallel mLSTM recurrence =================
// ---- 1. gate scan: 1 block per batch b, 64 threads = 8 heads x 8 chunks ----
__global__ __launch_bounds__(64) void mscan_kernel(const float* __restrict__ gates,
                                                   float* __restrict__ wAo, float* __restrict__ go,
                                                   float* __restrict__ mprev, float* __restrict__ alpha) {
    const int b = blockIdx.x;
    const int lane = threadIdx.x;
    const int hd = lane >> 3, c = lane & 7;
    const size_t gbase = ((size_t)b * S_ + c * LCH) * 16;
    float F = 0.f, I = -1e30f;
    for (int t = 0; t < LCH; ++t) {
        const float fi = gates[gbase + t * 16 + hd];
        const float ff = gates[gbase + t * 16 + 8 + hd];
        I = fmaxf(I + ff, fi);
        F += ff;
    }
    float Fs = F, Is = I;
#pragma unroll
    for (int off = 1; off < 8; off <<= 1) {
        const float Fo = __shfl_up(Fs, off);
        const float Io = __shfl_up(Is, off);
        if (c >= off) { Is = fmaxf(Io + Fs, Is); Fs = Fo + Fs; }
    }
    const float Fe = __shfl_up(Fs, 1);
    const float Ie = __shfl_up(Is, 1);
    const float mp = (c == 0) ? 0.f : fmaxf(Fe, Ie);
    float m = mp; F = 0.f;
    const size_t wbase = ((size_t)(b * NH_ + hd)) * S_ + c * LCH;
    for (int t = 0; t < LCH; ++t) {
        const float fi = gates[gbase + t * 16 + hd];
        const float ff = gates[gbase + t * 16 + 8 + hd];
        F += ff;
        m = fmaxf(ff + m, fi);
        wAo[wbase + t] = fi - F;
        go[wbase + t] = F - m;
    }
    const int idx = (b * NH_ + hd) * NCH + c;
    mprev[idx] = mp;
    alpha[idx] = __expf(fminf(mp + F - m, 0.f));
}

// ---- 2. chunk summaries: B_c = sum coeff_s v_s k_s^T; nB rides as vT row 96 = coeff ----
__global__ __launch_bounds__(512) void chunkA_kernel(
    const bf16_t* __restrict__ kb, const bf16_t* __restrict__ vb,
    const float* __restrict__ wAo, const float* __restrict__ go,
    float* __restrict__ Bst) {
    const int c = blockIdx.x, bh = blockIdx.y;
    const int b = bh >> 3, hd = bh & 7;
    __shared__ bf16_t kT[96 * 136];
    __shared__ bf16_t vTh[112 * 136];    // rows 0..95 = coeff*v^T, row 96 = coeff, 97..111 = 0
    __shared__ float coeffL[128];
    const int tid = threadIdx.x, lane = tid & 63, wid = tid >> 6;
    const int l15 = lane & 15, l4 = lane >> 4;
    const int s0 = c * LCH;
    const size_t seqb = (size_t)bh * S_;
    const float gend = go[seqb + s0 + LCH - 1];
    f32x4 acc[6];
#pragma unroll
    for (int nf = 0; nf < 6; ++nf) acc[nf] = f32x4{0.f, 0.f, 0.f, 0.f};

    {   // zero pad rows 97..111 once
        const bf16_t z16 = __float2bfloat16(0.f);
        for (int i = tid; i < 15 * 136; i += 512) vTh[97 * 136 + i] = z16;
    }

    for (int sb = 0; sb < 2; ++sb) {
        __syncthreads();
        if (tid < 128) {
            const float cf = __expf(fminf(wAo[seqb + s0 + sb * 128 + tid] + gend, 0.f));
            coeffL[tid] = cf;
            vTh[96 * 136 + tid] = __float2bfloat16(cf);
        }
        __syncthreads();
        {
            const int st = tid >> 2, e0 = (tid & 3) * 24;
            const size_t rowb = (size_t)(b * S_ + s0 + sb * 128 + st) * HID_ + hd * DH_ + e0;
            const float cf = coeffL[st];
#pragma unroll
            for (int jj = 0; jj < 3; ++jj) {
                const u16x8 kv = *(const u16x8*)(kb + rowb + jj * 8);
                const u16x8 vv = *(const u16x8*)(vb + rowb + jj * 8);
#pragma unroll
                for (int u = 0; u < 8; ++u) {
                    const int e = e0 + jj * 8 + u;
                    kT[e * 136 + st] = u2b(kv[u]);
                    vTh[e * 136 + st] = __float2bfloat16(b2f(vv[u]) * cf);
                }
            }
        }
        __syncthreads();
        if (wid < 7) {
#pragma unroll
            for (int ks = 0; ks < 4; ++ks) {
                const s16x8 af = *(const s16x8*)((const char*)vTh + (wid * 16 + l15) * 272 + ks * 64 + l4 * 16);
#pragma unroll
                for (int nf = 0; nf < 6; ++nf) {
                    const s16x8 bf = *(const s16x8*)((const char*)kT + (nf * 16 + l15) * 272 + ks * 64 + l4 * 16);
                    acc[nf] = __builtin_amdgcn_mfma_f32_16x16x32_bf16(af, bf, acc[nf], 0, 0, 0);
                }
            }
        }
    }
    float* outp = Bst + ((size_t)bh * NCH + c) * 9312;
    if (wid < 6) {
#pragma unroll
        for (int nf = 0; nf < 6; ++nf)
#pragma unroll
            for (int r = 0; r < 4; ++r)
                outp[(size_t)(wid * 16 + l4 * 4 + r) * 96 + nf * 16 + l15] = acc[nf][r];
    } else if (wid == 6 && l4 == 0) {
        // row 96 = nB (coeff-weighted k sum)
#pragma unroll
        for (int nf = 0; nf < 6; ++nf)
            outp[9216 + nf * 16 + l15] = acc[nf][0];
    }
}

// ---- 3. inter-chunk scan, in-place ----
__global__ __launch_bounds__(96) void chunkB_kernel(float* __restrict__ Bst,
                                                    const float* __restrict__ alpha) {
    const int idx = blockIdx.x * 96 + threadIdx.x;
    const int bh = blockIdx.y;
    float val = (idx < 9216) ? 0.f : 1.f;
    for (int c = 0; c < NCH; ++c) {
        float* p = Bst + ((size_t)bh * NCH + c) * 9312 + idx;
        const float t = *p;
        *p = val;
        val = alpha[bh * NCH + c] * val + t;
    }
}

// ---- 4. outputs: h = o * (inter + intra)/max(den,1), 64 q-rows per block ----
__global__ __launch_bounds__(256) void chunkC_kernel(
    const bf16_t* __restrict__ qb, const bf16_t* __restrict__ kb,
    const bf16_t* __restrict__ vb, const bf16_t* __restrict__ ob,
    const float* __restrict__ wAo, const float* __restrict__ go,
    const float* __restrict__ mprev, const float* __restrict__ Cst,
    float* __restrict__ hb) {
    const int c = blockIdx.x >> 2, qblk = blockIdx.x & 3;
    const int bh = blockIdx.y, b = bh >> 3, hd = bh & 7;
    __shared__ bf16_t Qs[64 * 104];
    __shared__ bf16_t Ks[64 * 104];
    __shared__ bf16_t vTs[112 * 72];      // rows 0..95 = V^T tile, row 96 = ones (den), 97..111 = 0
    __shared__ bf16_t Phs[64 * 72];
    __shared__ bf16_t CsH[112 * 104];     // rows 0..95 = C_start, row 96 = n_start, 97..111 = 0
    __shared__ float wAL[256];
    __shared__ float gL[64];
    __shared__ float scL[64];
    const int tid = threadIdx.x, lane = tid & 63, wid = tid >> 6;
    const int l15 = lane & 15, l4 = lane >> 4;
    const int s0 = c * LCH;
    const size_t seqb = (size_t)bh * S_;
    const int tq0 = b * S_ + s0 + qblk * 64;

    wAL[tid] = wAo[seqb + s0 + tid];
    if (tid < 64) {
        const float gg = go[seqb + s0 + qblk * 64 + tid];
        gL[tid] = gg;
        scL[tid] = __expf(fminf(mprev[bh * NCH + c] + gg, 0.f));
    }
    {
        const int tt = tid >> 2, e0 = (tid & 3) * 24;
        const bf16_t* qrow = qb + (size_t)(tq0 + tt) * HID_ + hd * DH_ + e0;
#pragma unroll
        for (int jj = 0; jj < 3; ++jj)
            *(u16x8*)&Qs[tt * 104 + e0 + jj * 8] = *(const u16x8*)(qrow + jj * 8);
    }
    {
        const float* Csp = Cst + ((size_t)bh * NCH + c) * 9312;
        for (int i = tid; i < 9312; i += 256) {
            int dd, ee;
            if (i < 9216) { dd = i / 96; ee = i - dd * 96; }
            else          { dd = 96;     ee = i - 9216; }
            CsH[dd * 104 + ee] = __float2bfloat16(Csp[i]);
        }
        const bf16_t z16 = __float2bfloat16(0.f);
        for (int i = tid; i < 15 * 104; i += 256) CsH[97 * 104 + i] = z16;
        if (tid < 64) vTs[96 * 72 + tid] = __float2bfloat16(1.f);
        for (int i = tid; i < 15 * 72; i += 256) vTs[97 * 72 + i] = z16;
    }
    __syncthreads();

    // inter: acc = Q @ Cs^T, then scale rows by exp(m_prev + g_tau)
    f32x4 acc[7];
#pragma unroll
    for (int nf = 0; nf < 7; ++nf) acc[nf] = f32x4{0.f, 0.f, 0.f, 0.f};
#pragma unroll
    for (int ks = 0; ks < 3; ++ks) {
        const s16x8 af = *(const s16x8*)((const char*)Qs + (wid * 16 + l15) * 208 + ks * 64 + l4 * 16);
#pragma unroll
        for (int nf = 0; nf < 7; ++nf) {
            const s16x8 bf = *(const s16x8*)((const char*)CsH + (nf * 16 + l15) * 208 + ks * 64 + l4 * 16);
            acc[nf] = __builtin_amdgcn_mfma_f32_16x16x32_bf16(af, bf, acc[nf], 0, 0, 0);
        }
    }
    {
        float scr[4];
#pragma unroll
        for (int r = 0; r < 4; ++r) scr[r] = scL[wid * 16 + l4 * 4 + r];
#pragma unroll
        for (int nf = 0; nf < 7; ++nf)
#pragma unroll
            for (int r = 0; r < 4; ++r) acc[nf][r] *= scr[r];
    }

    // intra: sigma-tiles of 64 up to (and including, masked) the diagonal tile
    for (int sb = 0; sb <= qblk; ++sb) {
        __syncthreads();
        {
            const int tt = tid >> 2, e0 = (tid & 3) * 24;
            const size_t rowb = (size_t)(b * S_ + s0 + sb * 64 + tt) * HID_ + hd * DH_ + e0;
#pragma unroll
            for (int jj = 0; jj < 3; ++jj) {
                *(u16x8*)&Ks[tt * 104 + e0 + jj * 8] = *(const u16x8*)(kb + rowb + jj * 8);
                const u16x8 vv = *(const u16x8*)(vb + rowb + jj * 8);
#pragma unroll
                for (int u = 0; u < 8; ++u)
                    vTs[(e0 + jj * 8 + u) * 72 + tt] = u2b(vv[u]);
            }
        }
        __syncthreads();
        f32x4 pacc[4];
#pragma unroll
        for (int nf = 0; nf < 4; ++nf) pacc[nf] = f32x4{0.f, 0.f, 0.f, 0.f};
#pragma unroll
        for (int ks = 0; ks < 3; ++ks) {
            const s16x8 af = *(const s16x8*)((const char*)Qs + (wid * 16 + l15) * 208 + ks * 64 + l4 * 16);
#pragma unroll
            for (int nf = 0; nf < 4; ++nf) {
                const s16x8 bf = *(const s16x8*)((const char*)Ks + (nf * 16 + l15) * 208 + ks * 64 + l4 * 16);
                pacc[nf] = __builtin_amdgcn_mfma_f32_16x16x32_bf16(af, bf, pacc[nf], 0, 0, 0);
            }
        }
#pragma unroll
        for (int nf = 0; nf < 4; ++nf) {
#pragma unroll
            for (int r = 0; r < 4; ++r) {
                const int tr = wid * 16 + l4 * 4 + r;
                const int sg = nf * 16 + l15;
                float p = 0.f;
                if (sb < qblk || sg <= tr)
                    p = pacc[nf][r] * __expf(fminf(wAL[sb * 64 + sg] + gL[tr], 0.f));
                Phs[tr * 72 + sg] = __float2bfloat16(p);
            }
        }
        __syncthreads();
#pragma unroll
        for (int ks = 0; ks < 2; ++ks) {
            const s16x8 af = *(const s16x8*)((const char*)Phs + (wid * 16 + l15) * 144 + ks * 64 + l4 * 16);
#pragma unroll
            for (int nf = 0; nf < 7; ++nf) {
                const s16x8 bf = *(const s16x8*)((const char*)vTs + (nf * 16 + l15) * 144 + ks * 64 + l4 * 16);
                acc[nf] = __builtin_amdgcn_mfma_f32_16x16x32_bf16(af, bf, acc[nf], 0, 0, 0);
            }
        }
    }

#pragma unroll
    for (int r = 0; r < 4; ++r) {
        float den = __shfl(acc[6][r], lane & 48);
        den = fmaxf(den, 1.0f);
        const int tr = wid * 16 + l4 * 4 + r;
        const size_t rowb = (size_t)(tq0 + tr) * HID_ + hd * DH_;
#pragma unroll
        for (int nf = 0; nf < 6; ++nf) {
            const int dc = nf * 16 + l15;
            const float o = __bfloat162float(ob[rowb + dc]);
            hb[rowb + dc] = o * acc[nf][r] / den;
        }
    }
}

// ---------------- (LN(h)+skip)*silu(r) -> compact bf16 pre [T,768] ----------------
__global__ __launch_bounds__(256) void epi1_kernel(const float* __restrict__ h,
                                                   const bf16_t* __restrict__ xskip,
                                                   const bf16_t* __restrict__ r,
                                                   const float* __restrict__ hw,
                                                   const float* __restrict__ hbi,
                                                   bf16_t* __restrict__ pre) {
    const int t = blockIdx.x, tid = threadIdx.x;
    const size_t rb = (size_t)t * HID_;
    float v0 = h[rb + tid], v1 = h[rb + tid + 256], v2 = h[rb + tid + 512];
    float sm = v0 + v1 + v2;
    float sq = v0 * v0 + v1 * v1 + v2 * v2;
#pragma unroll
    for (int off = 32; off > 0; off >>= 1) { sm += __shfl_xor(sm, off); sq += __shfl_xor(sq, off); }
    __shared__ float ws4[8];
    const int wid = tid >> 6, lane = tid & 63;
    if (lane == 0) { ws4[wid] = sm; ws4[4 + wid] = sq; }
    __syncthreads();
    sm = ws4[0] + ws4[1] + ws4[2] + ws4[3];
    sq = ws4[4] + ws4[5] + ws4[6] + ws4[7];
    const float mu = sm * (1.f / HID_);
    const float rs = rsqrtf(sq * (1.f / HID_) - mu * mu + 1e-6f);
    bf16_t* row = pre + (size_t)t * HID_;
#pragma unroll
    for (int k2 = 0; k2 < 3; ++k2) {
        const int c = tid + k2 * 256;
        const float v = (k2 == 0 ? v0 : k2 == 1 ? v1 : v2);
        float o = (v - mu) * rs * hw[c] + hbi[c] + __bfloat162float(xskip[rb + c]);
        const float rv = __bfloat162float(r[rb + c]);
        o *= rv * (1.f / (1.f + __expf(-rv)));
        row[c] = __float2bfloat16(o);
    }
}

extern "C" void kernel_launch(void* const* d_in, const int* in_sizes, int n_in,
                              void* d_out, int out_size, void* d_ws, size_t ws_size,
                              hipStream_t stream) {
    const float* x      = (const float*)d_in[0];
    const float* ln_w   = (const float*)d_in[1];
    const float* ln_b   = (const float*)d_in[2];
    const float* up_l_w = (const float*)d_in[3];
    const float* up_r_w = (const float*)d_in[4];
    const float* conv_w = (const float*)d_in[5];
    const float* skip_w = (const float*)d_in[6];
    const float* fused_w= (const float*)d_in[7];
    const float* fused_b= (const float*)d_in[8];
    const float* hid_w  = (const float*)d_in[9];
    const float* hid_b  = (const float*)d_in[10];
    const float* down_w = (const float*)d_in[11];
    float* out = (float*)d_out;
    (void)n_in; (void)out_size; (void)ws_size;

    const size_t T = (size_t)in_sizes[0] / D_;   // 16384
    const int B = (int)(T / S_);                 // 8

    // ---- workspace layout (< proven-safe 231.9 MB) ----
    char* ws = (char*)d_ws;
    size_t off = 0;
    auto take = [&](size_t bytes) -> char* {
        char* p = ws + off; off = (off + bytes + 255) & ~(size_t)255; return p;
    };
    // recurrence arena; the up/cat weights alias inside (dead before recurrence)
    char* arena = take(20123904);
    bf16_t* win_h = (bf16_t*)(arena);                       // [2304,768]  3,538,944 B
    bf16_t* win_l = (bf16_t*)(arena + 3538944);             // 3,538,944 B
    bf16_t* wcat  = (bf16_t*)(arena + 7077888);             // [3840,1536] 11,796,480 B (ends 18.9MB)
    float* Bst    = (float*)(arena);                        // 19,070,976 B
    float* wAarr  = (float*)(arena + 19071232);
    float* garr   = (float*)(arena + 19595520);
    float* mprevA = (float*)(arena + 20119808);
    float* alphaA = (float*)(arena + 20121856);

    bf16_t* wdn_h = (bf16_t*)take((size_t)D_ * HID_ * 2);   // survives until final GEMM
    char*   xnreg = take(T * 1536 * 2);   // xn compact bf16 -> xc-hi plane -> h fp32
    char*   big   = take(T * 1536 * 4);   // xl fp32 -> [o|q|k|v] bf16 -> pre bf16
    bf16_t* rbuf  = (bf16_t*)take(T * HID_ * 2);
    bf16_t* skipb = (bf16_t*)take(T * HID_ * 2);
    float*  gates = (float*)take(T * 16 * 4);

    bf16_t* xn   = (bf16_t*)xnreg;        // [T,768] bf16
    bf16_t* xch  = (bf16_t*)xnreg;        // [T,1536] bf16 (after xn dies)
    float*  h    = (float*)xnreg;         // [T,768] fp32 (after xch dies)
    float*  xl   = (float*)big;
    bf16_t* obuf = (bf16_t*)big;
    bf16_t* qbuf = (bf16_t*)(big + T * HID_ * 2);
    bf16_t* kbuf = (bf16_t*)(big + T * HID_ * 4);
    bf16_t* vbuf = (bf16_t*)(big + T * HID_ * 6);
    bf16_t* pre  = (bf16_t*)big;          // compact [T,768] (over o,q; dead)

    const int MT = (int)(T / 256);   // 64

    // 1. all weight conversions in one launch
    cvt_all_kernel<<<2048, 256, 0, stream>>>(up_l_w, up_r_w, skip_w, fused_w, down_w,
                                             win_h, win_l, wcat, wdn_h);
    // 2. LayerNorm -> compact xn
    ln_x_kernel<<<(int)T, 256, 0, stream>>>(x, ln_w, ln_b, xn);
    // 3. merged [xl | r] = xn @ [up_l|up_r]^T (2-pass: Wh + Wl)  N=2304, K=768
    gemm256<2, 4, 12><<<dim3(2304 / 256, MT), 512, 0, stream>>>(
        (const char*)xn, 1536, 0, win_h, win_l,
        rbuf, xl, 0, nullptr, nullptr, nullptr, nullptr, nullptr, nullptr);
    // 4. conv+silu -> compact xc-hi plane (xn dead); exact fp32 gates fused in
    conv_gate_kernel<<<(int)T, 192, 0, stream>>>(xl, conv_w, fused_w, fused_b, xch, gates);
    // 5. merged [skip | o,q,k,v] = xc_hi @ wcat^T (1-pass, N=3840)  K=1536
    gemm256<1, 2, 24><<<dim3(3840 / 256, MT), 512, 0, stream>>>(
        (const char*)xch, 3072, 0, wcat, nullptr,
        skipb, nullptr, 0, obuf, qbuf, kbuf, vbuf, fused_b + 16, nullptr);
    // 6. chunkwise-parallel recurrence -> h fp32 (arena weights dead now)
    mscan_kernel<<<B, 64, 0, stream>>>(gates, wAarr, garr, mprevA, alphaA);
    chunkA_kernel<<<dim3(NCH, B * NH_), 512, 0, stream>>>(kbuf, vbuf, wAarr, garr, Bst);
    chunkB_kernel<<<dim3(97, B * NH_), 96, 0, stream>>>(Bst, alphaA);
    chunkC_kernel<<<dim3(NCH * 4, B * NH_), 256, 0, stream>>>(qbuf, kbuf, vbuf, obuf,
                                                              wAarr, garr, mprevA, Bst, h);
    // 7. (LN(h)+skip)*silu(r) -> compact pre
    epi1_kernel<<<(int)T, 256, 0, stream>>>(h, skipb, rbuf, hid_w, hid_b, pre);
    // 8. out = pre @ down^T + x (1-pass)  K=768
    gemm256<1, 3, 12><<<dim3(HID_ / 256, MT), 512, 0, stream>>>(
        (const char*)pre, 1536, 0, wdn_h, nullptr,
        nullptr, out, HID_, nullptr, nullptr, nullptr, nullptr, nullptr, x);
}